// Round 1
// baseline (716.241 us; speedup 1.0000x reference)
//
#include <hip/hip_runtime.h>
#include <math.h>

#define N_NODES 50000
#define N_EDGES 800000
#define IN_F    256
#define HID_F   128
#define OUT_F   40
#define W0N     (3*HID_F)   // 384
#define W1N     (3*OUT_F)   // 120
#define NB      ((N_NODES + 255) / 256)   // 196 scan blocks

static __device__ __forceinline__ float sigmoidf_(float x) {
    return 1.0f / (1.0f + expf(-x));
}

// ---------------- CSR build ----------------

__global__ void k_count(const int* __restrict__ ei, int* __restrict__ deg) {
    int e = blockIdx.x * blockDim.x + threadIdx.x;
    if (e < N_EDGES) atomicAdd(&deg[ei[e]], 1);
}

__global__ void k_dinv(const int* __restrict__ deg, float* __restrict__ dinv) {
    int i = blockIdx.x * blockDim.x + threadIdx.x;
    if (i < N_NODES) dinv[i] = 1.0f / (1.0f + (float)deg[i]);
}

// local inclusive scan per 256-block; block totals out
__global__ void k_scan1(const int* __restrict__ deg, int* __restrict__ rowPtr,
                        int* __restrict__ blkTot) {
    __shared__ int s[256];
    int t = threadIdx.x;
    int gid = blockIdx.x * 256 + t;
    int v = (gid < N_NODES) ? deg[gid] : 0;
    s[t] = v; __syncthreads();
    for (int d = 1; d < 256; d <<= 1) {
        int x = (t >= d) ? s[t - d] : 0;
        __syncthreads();
        s[t] += x;
        __syncthreads();
    }
    if (gid < N_NODES) rowPtr[gid] = s[t];      // local inclusive
    if (t == 255) blkTot[blockIdx.x] = s[255];
}

// in-place exclusive scan of block totals (NB <= 256), single block
__global__ void k_scan2(int* __restrict__ blk) {
    __shared__ int s[256];
    int t = threadIdx.x;
    int v = (t < NB) ? blk[t] : 0;
    s[t] = v; __syncthreads();
    for (int d = 1; d < 256; d <<= 1) {
        int x = (t >= d) ? s[t - d] : 0;
        __syncthreads();
        s[t] += x;
        __syncthreads();
    }
    if (t < NB) blk[t] = s[t] - v;              // exclusive
}

__global__ void k_scan3(const int* __restrict__ deg, const int* __restrict__ blkOff,
                        int* __restrict__ rowPtr) {
    int t = threadIdx.x;
    int gid = blockIdx.x * 256 + t;
    if (gid < N_NODES) rowPtr[gid] += blkOff[blockIdx.x] - deg[gid];  // exclusive global
    if (gid == 0) rowPtr[N_NODES] = N_EDGES;
}

__global__ void k_fill(const int* __restrict__ ei, const int* __restrict__ rowPtr,
                       int* __restrict__ cursor, int* __restrict__ colIdx) {
    int e = blockIdx.x * blockDim.x + threadIdx.x;
    if (e < N_EDGES) {
        int r = ei[e];
        int c = ei[N_EDGES + e];
        int pos = rowPtr[r] + atomicAdd(&cursor[r], 1);
        colIdx[pos] = c;
    }
}

// ---------------- weight packing: W = [Wl | Wh | Wm], rows x (3*sub) ----------------

__global__ void k_pack(const float* __restrict__ Wl, const float* __restrict__ Wh,
                       const float* __restrict__ Wm, float* __restrict__ W,
                       int rows, int sub) {
    int i = blockIdx.x * blockDim.x + threadIdx.x;
    int cols = 3 * sub;
    if (i < rows * cols) {
        int r = i / cols, c = i % cols;
        float v;
        if (c < sub)            v = Wl[r * sub + c];
        else if (c < 2 * sub)   v = Wh[r * sub + (c - sub)];
        else                    v = Wm[r * sub + (c - 2 * sub)];
        W[i] = v;
    }
}

// ---------------- fp32 tiled GEMM: C[M,N] = A[M,K] @ B[K,N] ----------------

#define BM 64
#define BN 64
#define BK 16
__global__ __launch_bounds__(256) void k_gemm(const float* __restrict__ A,
                                              const float* __restrict__ B,
                                              float* __restrict__ C,
                                              int M, int N, int K) {
    __shared__ float As[BK][BM + 1];
    __shared__ float Bs[BK][BN + 1];
    int bm = blockIdx.y * BM, bn = blockIdx.x * BN;
    int tid = threadIdx.x;
    int tr = tid >> 4, tc = tid & 15;
    float acc[4][4] = {};
    for (int k0 = 0; k0 < K; k0 += BK) {
        for (int idx = tid; idx < BM * BK; idx += 256) {
            int m = idx >> 4, kk = idx & 15;
            int gm = bm + m;
            As[kk][m] = (gm < M) ? A[(size_t)gm * K + k0 + kk] : 0.f;
        }
        for (int idx = tid; idx < BK * BN; idx += 256) {
            int kk = idx >> 6, n = idx & 63;
            int gn = bn + n;
            Bs[kk][n] = (gn < N) ? B[(size_t)(k0 + kk) * N + gn] : 0.f;
        }
        __syncthreads();
#pragma unroll
        for (int kk = 0; kk < BK; ++kk) {
            float a[4], b[4];
#pragma unroll
            for (int u = 0; u < 4; ++u) a[u] = As[kk][tr * 4 + u];
#pragma unroll
            for (int u = 0; u < 4; ++u) b[u] = Bs[kk][tc * 4 + u];
#pragma unroll
            for (int u = 0; u < 4; ++u)
#pragma unroll
                for (int v = 0; v < 4; ++v)
                    acc[u][v] += a[u] * b[v];
        }
        __syncthreads();
    }
    for (int u = 0; u < 4; ++u) {
        int gm = bm + tr * 4 + u;
        if (gm >= M) continue;
        for (int v = 0; v < 4; ++v) {
            int gn = bn + tc * 4 + v;
            if (gn < N) C[(size_t)gm * N + gn] = acc[u][v];
        }
    }
}

// ---------------- layer 0: aggregate + ACM epilogue (256 thr = 2*HID_F) ----------------
// H layout per node: [hl(128) | hh(128) | hm(128)]

__global__ __launch_bounds__(256) void k_layer0(
        const float* __restrict__ H, const int* __restrict__ rowPtr,
        const int* __restrict__ colIdx, const float* __restrict__ dinv,
        const float* __restrict__ al, const float* __restrict__ ah,
        const float* __restrict__ am, const float* __restrict__ att,
        float* __restrict__ hout) {
    int i = blockIdx.x;
    int t = threadIdx.x;
    int p0 = rowPtr[i], p1 = rowPtr[i + 1];
    float acc = 0.f;
    for (int p = p0; p < p1; ++p) {
        int j = colIdx[p];
        acc += H[(size_t)j * W0N + t];
    }
    float selfv = H[(size_t)i * W0N + t];
    float di = dinv[i];
    float lowv = di * (selfv + acc);

    __shared__ float red[256];
    __shared__ float ohs[HID_F];
    __shared__ float svals[3];

    float ol = 0.f, oh = 0.f, om = 0.f, pr;
    if (t < HID_F) {
        ol = fmaxf(lowv, 0.f);
        om = fmaxf(H[(size_t)i * W0N + 2 * HID_F + t], 0.f);
        pr = ol * al[t];
    } else {
        oh = fmaxf(selfv - lowv, 0.f);
        ohs[t - HID_F] = oh;
        pr = oh * ah[t - HID_F];
    }
    red[t] = pr; __syncthreads();
    // reduce each 128-half independently
    for (int s2 = 64; s2 > 0; s2 >>= 1) {
        if ((t & 127) < s2) red[t] += red[t + s2];
        __syncthreads();
    }
    if (t == 0)   svals[0] = red[0];
    if (t == 128) svals[1] = red[128];
    __syncthreads();
    red[t] = (t < HID_F) ? om * am[t] : 0.f;
    __syncthreads();
    for (int s2 = 128; s2 > 0; s2 >>= 1) {
        if (t < s2) red[t] += red[t + s2];
        __syncthreads();
    }
    if (t == 0) svals[2] = red[0];
    __syncthreads();

    if (t < HID_F) {
        float sg0 = sigmoidf_(svals[0]);
        float sg1 = sigmoidf_(svals[1]);
        float sg2 = sigmoidf_(svals[2]);
        const float inv3 = (1.0f / 3.0f);
        float e0 = (sg0 * att[0] + sg1 * att[3] + sg2 * att[6]) * inv3;
        float e1 = (sg0 * att[1] + sg1 * att[4] + sg2 * att[7]) * inv3;
        float e2 = (sg0 * att[2] + sg1 * att[5] + sg2 * att[8]) * inv3;
        float m = fmaxf(e0, fmaxf(e1, e2));
        float x0 = expf(e0 - m), x1 = expf(e1 - m), x2 = expf(e2 - m);
        float inv = 1.0f / (x0 + x1 + x2);
        hout[(size_t)i * HID_F + t] = 3.0f * inv * (x0 * ol + x1 * ohs[t] + x2 * om);
    }
}

// ---------------- layer 1: aggregate + ACM epilogue (128 thr, 120 feats) ----------------
// H layout per node: [hl(40) | hh(40) | hm(40)]

__global__ __launch_bounds__(128) void k_layer1(
        const float* __restrict__ H, const int* __restrict__ rowPtr,
        const int* __restrict__ colIdx, const float* __restrict__ dinv,
        const float* __restrict__ al, const float* __restrict__ ah,
        const float* __restrict__ am, const float* __restrict__ att,
        float* __restrict__ out) {
    int i = blockIdx.x;
    int t = threadIdx.x;
    int p0 = rowPtr[i], p1 = rowPtr[i + 1];
    float acc = 0.f;
    if (t < 2 * OUT_F) {
        for (int p = p0; p < p1; ++p) {
            int j = colIdx[p];
            acc += H[(size_t)j * W1N + t];
        }
    }
    float selfv = (t < W1N) ? H[(size_t)i * W1N + t] : 0.f;
    float di = dinv[i];

    __shared__ float red[128];
    __shared__ float ohs[OUT_F];
    __shared__ float oms[OUT_F];
    __shared__ float svals[3];

    float val = 0.f, pr = 0.f;
    if (t < OUT_F) {
        val = fmaxf(di * (selfv + acc), 0.f);            // out_low
        pr = val * al[t];
    } else if (t < 2 * OUT_F) {
        float lowv = di * (selfv + acc);
        val = fmaxf(selfv - lowv, 0.f);                  // out_high
        ohs[t - OUT_F] = val;
        pr = val * ah[t - OUT_F];
    } else if (t < 3 * OUT_F) {
        val = fmaxf(selfv, 0.f);                         // out_mlp
        oms[t - 2 * OUT_F] = val;
        pr = val * am[t - 2 * OUT_F];
    }
    red[t] = pr; __syncthreads();
    if (t < 3) {
        float s = 0.f;
        for (int q = 0; q < OUT_F; ++q) s += red[t * OUT_F + q];
        svals[t] = s;
    }
    __syncthreads();

    if (t < OUT_F) {
        float sg0 = sigmoidf_(svals[0]);
        float sg1 = sigmoidf_(svals[1]);
        float sg2 = sigmoidf_(svals[2]);
        const float inv3 = (1.0f / 3.0f);
        float e0 = (sg0 * att[0] + sg1 * att[3] + sg2 * att[6]) * inv3;
        float e1 = (sg0 * att[1] + sg1 * att[4] + sg2 * att[7]) * inv3;
        float e2 = (sg0 * att[2] + sg1 * att[5] + sg2 * att[8]) * inv3;
        float m = fmaxf(e0, fmaxf(e1, e2));
        float x0 = expf(e0 - m), x1 = expf(e1 - m), x2 = expf(e2 - m);
        float inv = 1.0f / (x0 + x1 + x2);
        out[(size_t)i * OUT_F + t] = 3.0f * inv * (x0 * val + x1 * ohs[t] + x2 * oms[t]);
    }
}

// ---------------- launch ----------------

extern "C" void kernel_launch(void* const* d_in, const int* in_sizes, int n_in,
                              void* d_out, int out_size, void* d_ws, size_t ws_size,
                              hipStream_t stream) {
    const float* x    = (const float*)d_in[0];
    const int*   ei   = (const int*)d_in[1];
    const float* Wl0  = (const float*)d_in[2];
    const float* Wh0  = (const float*)d_in[3];
    const float* Wm0  = (const float*)d_in[4];
    const float* al0  = (const float*)d_in[5];
    const float* ah0  = (const float*)d_in[6];
    const float* am0  = (const float*)d_in[7];
    const float* att0 = (const float*)d_in[8];
    const float* Wl1  = (const float*)d_in[9];
    const float* Wh1  = (const float*)d_in[10];
    const float* Wm1  = (const float*)d_in[11];
    const float* al1  = (const float*)d_in[12];
    const float* ah1  = (const float*)d_in[13];
    const float* am1  = (const float*)d_in[14];
    const float* att1 = (const float*)d_in[15];
    float* out = (float*)d_out;

    char* ws = (char*)d_ws;
    size_t off = 0;
    auto alloc = [&](size_t bytes) -> char* {
        char* p = ws + off;
        off += (bytes + 255) & ~(size_t)255;
        return p;
    };
    int*   deg    = (int*)  alloc((size_t)N_NODES * 4);
    int*   cursor = (int*)  alloc((size_t)N_NODES * 4);
    int*   rowPtr = (int*)  alloc((size_t)(N_NODES + 1) * 4);
    int*   colIdx = (int*)  alloc((size_t)N_EDGES * 4);
    int*   blkTot = (int*)  alloc(256 * 4);
    float* dinv   = (float*)alloc((size_t)N_NODES * 4);
    float* W0p    = (float*)alloc((size_t)IN_F * W0N * 4);
    float* W1p    = (float*)alloc((size_t)HID_F * W1N * 4);
    float* H      = (float*)alloc((size_t)N_NODES * W0N * 4);  // H0, reused as H1
    float* hbuf   = (float*)alloc((size_t)N_NODES * HID_F * 4);

    const int EB = (N_EDGES + 255) / 256;   // 3125

    // CSR build
    hipMemsetAsync(deg, 0, (size_t)N_NODES * 4, stream);
    hipMemsetAsync(cursor, 0, (size_t)N_NODES * 4, stream);
    k_count<<<EB, 256, 0, stream>>>(ei, deg);
    k_dinv<<<NB, 256, 0, stream>>>(deg, dinv);
    k_scan1<<<NB, 256, 0, stream>>>(deg, rowPtr, blkTot);
    k_scan2<<<1, 256, 0, stream>>>(blkTot);
    k_scan3<<<NB, 256, 0, stream>>>(deg, blkTot, rowPtr);
    k_fill<<<EB, 256, 0, stream>>>(ei, rowPtr, cursor, colIdx);

    // layer 0
    k_pack<<<(IN_F * W0N + 255) / 256, 256, 0, stream>>>(Wl0, Wh0, Wm0, W0p, IN_F, HID_F);
    {
        dim3 grid((W0N + BN - 1) / BN, (N_NODES + BM - 1) / BM);
        k_gemm<<<grid, 256, 0, stream>>>(x, W0p, H, N_NODES, W0N, IN_F);
    }
    k_layer0<<<N_NODES, 256, 0, stream>>>(H, rowPtr, colIdx, dinv, al0, ah0, am0, att0, hbuf);

    // layer 1
    k_pack<<<(HID_F * W1N + 255) / 256, 256, 0, stream>>>(Wl1, Wh1, Wm1, W1p, HID_F, OUT_F);
    {
        dim3 grid((W1N + BN - 1) / BN, (N_NODES + BM - 1) / BM);
        k_gemm<<<grid, 256, 0, stream>>>(hbuf, W1p, H, N_NODES, W1N, HID_F);
    }
    k_layer1<<<N_NODES, 128, 0, stream>>>(H, rowPtr, colIdx, dinv, al1, ah1, am1, att1, out);
}

// Round 2
// 470.438 us; speedup vs baseline: 1.5225x; 1.5225x over previous
//
#include <hip/hip_runtime.h>
#include <math.h>

#define N_NODES 50000
#define N_EDGES 800000
#define IN_F    256
#define HID_F   128
#define OUT_F   40
#define W0N     (3*HID_F)   // 384
#define W1N     (3*OUT_F)   // 120
#define NB      ((N_NODES + 255) / 256)   // 196 scan blocks

typedef __attribute__((ext_vector_type(8))) unsigned short ushort8;
typedef __attribute__((ext_vector_type(8))) __bf16 bf16x8;
typedef __attribute__((ext_vector_type(4))) float f32x4;

static __device__ __forceinline__ float sigmoidf_(float x) {
    return 1.0f / (1.0f + expf(-x));
}

static __device__ __forceinline__ unsigned short f2bf(float f) {
    unsigned u = __float_as_uint(f);
    u += 0x7FFFu + ((u >> 16) & 1u);
    return (unsigned short)(u >> 16);
}

// ---------------- CSR build ----------------

__global__ void k_count(const int* __restrict__ ei, int* __restrict__ deg) {
    int e = blockIdx.x * blockDim.x + threadIdx.x;
    if (e < N_EDGES) atomicAdd(&deg[ei[e]], 1);
}

__global__ void k_dinv(const int* __restrict__ deg, float* __restrict__ dinv) {
    int i = blockIdx.x * blockDim.x + threadIdx.x;
    if (i < N_NODES) dinv[i] = 1.0f / (1.0f + (float)deg[i]);
}

__global__ void k_scan1(const int* __restrict__ deg, int* __restrict__ rowPtr,
                        int* __restrict__ blkTot) {
    __shared__ int s[256];
    int t = threadIdx.x;
    int gid = blockIdx.x * 256 + t;
    int v = (gid < N_NODES) ? deg[gid] : 0;
    s[t] = v; __syncthreads();
    for (int d = 1; d < 256; d <<= 1) {
        int x = (t >= d) ? s[t - d] : 0;
        __syncthreads();
        s[t] += x;
        __syncthreads();
    }
    if (gid < N_NODES) rowPtr[gid] = s[t];
    if (t == 255) blkTot[blockIdx.x] = s[255];
}

__global__ void k_scan2(int* __restrict__ blk) {
    __shared__ int s[256];
    int t = threadIdx.x;
    int v = (t < NB) ? blk[t] : 0;
    s[t] = v; __syncthreads();
    for (int d = 1; d < 256; d <<= 1) {
        int x = (t >= d) ? s[t - d] : 0;
        __syncthreads();
        s[t] += x;
        __syncthreads();
    }
    if (t < NB) blk[t] = s[t] - v;
}

__global__ void k_scan3(const int* __restrict__ deg, const int* __restrict__ blkOff,
                        int* __restrict__ rowPtr) {
    int t = threadIdx.x;
    int gid = blockIdx.x * 256 + t;
    if (gid < N_NODES) rowPtr[gid] += blkOff[blockIdx.x] - deg[gid];
    if (gid == 0) rowPtr[N_NODES] = N_EDGES;
}

__global__ void k_fill(const int* __restrict__ ei, const int* __restrict__ rowPtr,
                       int* __restrict__ cursor, int* __restrict__ colIdx) {
    int e = blockIdx.x * blockDim.x + threadIdx.x;
    if (e < N_EDGES) {
        int r = ei[e];
        int c = ei[N_EDGES + e];
        int pos = rowPtr[r] + atomicAdd(&cursor[r], 1);
        colIdx[pos] = c;
    }
}

// ---------------- weight pack: Bt[n][k] = W[k][n], bf16, n = [Wl|Wh|Wm] ----------------

__global__ void k_packT(const float* __restrict__ Wl, const float* __restrict__ Wh,
                        const float* __restrict__ Wm, unsigned short* __restrict__ Bt,
                        int K, int sub) {
    int i = blockIdx.x * blockDim.x + threadIdx.x;
    int cols = 3 * sub;
    if (i < K * cols) {
        int n = i / K, k = i % K;
        float v;
        if (n < sub)            v = Wl[k * sub + n];
        else if (n < 2 * sub)   v = Wh[k * sub + (n - sub)];
        else                    v = Wm[k * sub + (n - 2 * sub)];
        Bt[i] = f2bf(v);
    }
}

// ---------------- bf16 MFMA GEMM: C[M,N] fp32 = A[M,K] @ Bt[N,K]^T ----------------
// tile 128x128, BK=32, 4 waves (2x2), each wave 64x64 = 4x4 frags of 16x16x32

#define BKP 40   // 32 + 8 pad (16B) -> row stride 80B, <=2-way LDS conflicts

template<bool CVT_A>
__global__ __launch_bounds__(256) void k_gemm_mfma(
        const void* __restrict__ Av, const unsigned short* __restrict__ Bt,
        float* __restrict__ C, int M, int N, int K) {
    __shared__ unsigned short As[128 * BKP];
    __shared__ unsigned short Bs[128 * BKP];
    int tid  = threadIdx.x;
    int lane = tid & 63, wid = tid >> 6;
    int wr = wid >> 1, wc = wid & 1;
    int bm = blockIdx.y * 128, bn = blockIdx.x * 128;

    int srow = tid >> 1;           // 0..127
    int scol = (tid & 1) * 16;     // 0 or 16

    int garow = min(bm + srow, M - 1);
    int gbrow = min(bn + srow, N - 1);

    const float*          Af = (const float*)Av;
    const unsigned short* Ab = (const unsigned short*)Av;

    f32x4 acc[4][4];
#pragma unroll
    for (int m = 0; m < 4; ++m)
#pragma unroll
        for (int n = 0; n < 4; ++n)
            acc[m][n] = (f32x4)(0.0f);

    int kg = (lane >> 4) * 8;
    int rA = wr * 64 + (lane & 15);
    int rB = wc * 64 + (lane & 15);

    for (int k0 = 0; k0 < K; k0 += 32) {
        // ---- stage A tile [128][32] ----
        if (CVT_A) {
            const float* src = Af + (size_t)garow * K + k0 + scol;
            float4 f0 = *(const float4*)(src);
            float4 f1 = *(const float4*)(src + 4);
            float4 f2 = *(const float4*)(src + 8);
            float4 f3 = *(const float4*)(src + 12);
            ushort8 u0, u1;
            u0[0]=f2bf(f0.x); u0[1]=f2bf(f0.y); u0[2]=f2bf(f0.z); u0[3]=f2bf(f0.w);
            u0[4]=f2bf(f1.x); u0[5]=f2bf(f1.y); u0[6]=f2bf(f1.z); u0[7]=f2bf(f1.w);
            u1[0]=f2bf(f2.x); u1[1]=f2bf(f2.y); u1[2]=f2bf(f2.z); u1[3]=f2bf(f2.w);
            u1[4]=f2bf(f3.x); u1[5]=f2bf(f3.y); u1[6]=f2bf(f3.z); u1[7]=f2bf(f3.w);
            *(ushort8*)&As[srow * BKP + scol]     = u0;
            *(ushort8*)&As[srow * BKP + scol + 8] = u1;
        } else {
            const unsigned short* src = Ab + (size_t)garow * K + k0 + scol;
            *(ushort8*)&As[srow * BKP + scol]     = *(const ushort8*)(src);
            *(ushort8*)&As[srow * BKP + scol + 8] = *(const ushort8*)(src + 8);
        }
        // ---- stage Bt tile [128][32] ----
        {
            const unsigned short* src = Bt + (size_t)gbrow * K + k0 + scol;
            *(ushort8*)&Bs[srow * BKP + scol]     = *(const ushort8*)(src);
            *(ushort8*)&Bs[srow * BKP + scol + 8] = *(const ushort8*)(src + 8);
        }
        __syncthreads();

        bf16x8 a[4], b[4];
#pragma unroll
        for (int m = 0; m < 4; ++m)
            a[m] = __builtin_bit_cast(bf16x8, *(const ushort8*)&As[(rA + m * 16) * BKP + kg]);
#pragma unroll
        for (int n = 0; n < 4; ++n)
            b[n] = __builtin_bit_cast(bf16x8, *(const ushort8*)&Bs[(rB + n * 16) * BKP + kg]);
#pragma unroll
        for (int m = 0; m < 4; ++m)
#pragma unroll
            for (int n = 0; n < 4; ++n)
                acc[m][n] = __builtin_amdgcn_mfma_f32_16x16x32_bf16(a[m], b[n], acc[m][n], 0, 0, 0);
        __syncthreads();
    }

    // ---- write C: col=lane&15, row=(lane>>4)*4+j ----
    int col  = lane & 15;
    int rsub = (lane >> 4) * 4;
#pragma unroll
    for (int m = 0; m < 4; ++m) {
        int gm0 = bm + wr * 64 + m * 16 + rsub;
#pragma unroll
        for (int n = 0; n < 4; ++n) {
            int gn = bn + wc * 64 + n * 16 + col;
            if (gn >= N) continue;
#pragma unroll
            for (int j = 0; j < 4; ++j) {
                int gm = gm0 + j;
                if (gm < M) C[(size_t)gm * N + gn] = acc[m][n][j];
            }
        }
    }
}

// ---------------- layer 0: aggregate + ACM epilogue (256 thr = 2*HID_F) ----------------
// H layout per node: [hl(128) | hh(128) | hm(128)]; output bf16 for GEMM1

__global__ __launch_bounds__(256) void k_layer0(
        const float* __restrict__ H, const int* __restrict__ rowPtr,
        const int* __restrict__ colIdx, const float* __restrict__ dinv,
        const float* __restrict__ al, const float* __restrict__ ah,
        const float* __restrict__ am, const float* __restrict__ att,
        unsigned short* __restrict__ hout) {
    int i = blockIdx.x;
    int t = threadIdx.x;
    int p0 = rowPtr[i], p1 = rowPtr[i + 1];
    float acc = 0.f;
    for (int p = p0; p < p1; ++p) {
        int j = colIdx[p];
        acc += H[(size_t)j * W0N + t];
    }
    float selfv = H[(size_t)i * W0N + t];
    float di = dinv[i];
    float lowv = di * (selfv + acc);

    __shared__ float red[256];
    __shared__ float ohs[HID_F];
    __shared__ float svals[3];

    float ol = 0.f, oh = 0.f, om = 0.f, pr;
    if (t < HID_F) {
        ol = fmaxf(lowv, 0.f);
        om = fmaxf(H[(size_t)i * W0N + 2 * HID_F + t], 0.f);
        pr = ol * al[t];
    } else {
        oh = fmaxf(selfv - lowv, 0.f);
        ohs[t - HID_F] = oh;
        pr = oh * ah[t - HID_F];
    }
    red[t] = pr; __syncthreads();
    for (int s2 = 64; s2 > 0; s2 >>= 1) {
        if ((t & 127) < s2) red[t] += red[t + s2];
        __syncthreads();
    }
    if (t == 0)   svals[0] = red[0];
    if (t == 128) svals[1] = red[128];
    __syncthreads();
    red[t] = (t < HID_F) ? om * am[t] : 0.f;
    __syncthreads();
    for (int s2 = 128; s2 > 0; s2 >>= 1) {
        if (t < s2) red[t] += red[t + s2];
        __syncthreads();
    }
    if (t == 0) svals[2] = red[0];
    __syncthreads();

    if (t < HID_F) {
        float sg0 = sigmoidf_(svals[0]);
        float sg1 = sigmoidf_(svals[1]);
        float sg2 = sigmoidf_(svals[2]);
        const float inv3 = (1.0f / 3.0f);
        float e0 = (sg0 * att[0] + sg1 * att[3] + sg2 * att[6]) * inv3;
        float e1 = (sg0 * att[1] + sg1 * att[4] + sg2 * att[7]) * inv3;
        float e2 = (sg0 * att[2] + sg1 * att[5] + sg2 * att[8]) * inv3;
        float m = fmaxf(e0, fmaxf(e1, e2));
        float x0 = expf(e0 - m), x1 = expf(e1 - m), x2 = expf(e2 - m);
        float inv = 1.0f / (x0 + x1 + x2);
        hout[(size_t)i * HID_F + t] = f2bf(3.0f * inv * (x0 * ol + x1 * ohs[t] + x2 * om));
    }
}

// ---------------- layer 1: aggregate + ACM epilogue (128 thr, 120 feats) ----------------

__global__ __launch_bounds__(128) void k_layer1(
        const float* __restrict__ H, const int* __restrict__ rowPtr,
        const int* __restrict__ colIdx, const float* __restrict__ dinv,
        const float* __restrict__ al, const float* __restrict__ ah,
        const float* __restrict__ am, const float* __restrict__ att,
        float* __restrict__ out) {
    int i = blockIdx.x;
    int t = threadIdx.x;
    int p0 = rowPtr[i], p1 = rowPtr[i + 1];
    float acc = 0.f;
    if (t < 2 * OUT_F) {
        for (int p = p0; p < p1; ++p) {
            int j = colIdx[p];
            acc += H[(size_t)j * W1N + t];
        }
    }
    float selfv = (t < W1N) ? H[(size_t)i * W1N + t] : 0.f;
    float di = dinv[i];

    __shared__ float red[128];
    __shared__ float ohs[OUT_F];
    __shared__ float oms[OUT_F];
    __shared__ float svals[3];

    float val = 0.f, pr = 0.f;
    if (t < OUT_F) {
        val = fmaxf(di * (selfv + acc), 0.f);
        pr = val * al[t];
    } else if (t < 2 * OUT_F) {
        float lowv = di * (selfv + acc);
        val = fmaxf(selfv - lowv, 0.f);
        ohs[t - OUT_F] = val;
        pr = val * ah[t - OUT_F];
    } else if (t < 3 * OUT_F) {
        val = fmaxf(selfv, 0.f);
        oms[t - 2 * OUT_F] = val;
        pr = val * am[t - 2 * OUT_F];
    }
    red[t] = pr; __syncthreads();
    if (t < 3) {
        float s = 0.f;
        for (int q = 0; q < OUT_F; ++q) s += red[t * OUT_F + q];
        svals[t] = s;
    }
    __syncthreads();

    if (t < OUT_F) {
        float sg0 = sigmoidf_(svals[0]);
        float sg1 = sigmoidf_(svals[1]);
        float sg2 = sigmoidf_(svals[2]);
        const float inv3 = (1.0f / 3.0f);
        float e0 = (sg0 * att[0] + sg1 * att[3] + sg2 * att[6]) * inv3;
        float e1 = (sg0 * att[1] + sg1 * att[4] + sg2 * att[7]) * inv3;
        float e2 = (sg0 * att[2] + sg1 * att[5] + sg2 * att[8]) * inv3;
        float m = fmaxf(e0, fmaxf(e1, e2));
        float x0 = expf(e0 - m), x1 = expf(e1 - m), x2 = expf(e2 - m);
        float inv = 1.0f / (x0 + x1 + x2);
        out[(size_t)i * OUT_F + t] = 3.0f * inv * (x0 * val + x1 * ohs[t] + x2 * oms[t]);
    }
}

// ---------------- launch ----------------

extern "C" void kernel_launch(void* const* d_in, const int* in_sizes, int n_in,
                              void* d_out, int out_size, void* d_ws, size_t ws_size,
                              hipStream_t stream) {
    const float* x    = (const float*)d_in[0];
    const int*   ei   = (const int*)d_in[1];
    const float* Wl0  = (const float*)d_in[2];
    const float* Wh0  = (const float*)d_in[3];
    const float* Wm0  = (const float*)d_in[4];
    const float* al0  = (const float*)d_in[5];
    const float* ah0  = (const float*)d_in[6];
    const float* am0  = (const float*)d_in[7];
    const float* att0 = (const float*)d_in[8];
    const float* Wl1  = (const float*)d_in[9];
    const float* Wh1  = (const float*)d_in[10];
    const float* Wm1  = (const float*)d_in[11];
    const float* al1  = (const float*)d_in[12];
    const float* ah1  = (const float*)d_in[13];
    const float* am1  = (const float*)d_in[14];
    const float* att1 = (const float*)d_in[15];
    float* out = (float*)d_out;

    char* ws = (char*)d_ws;
    size_t off = 0;
    auto alloc = [&](size_t bytes) -> char* {
        char* p = ws + off;
        off += (bytes + 255) & ~(size_t)255;
        return p;
    };
    int*   deg    = (int*)  alloc((size_t)N_NODES * 4);
    int*   cursor = (int*)  alloc((size_t)N_NODES * 4);
    int*   rowPtr = (int*)  alloc((size_t)(N_NODES + 1) * 4);
    int*   colIdx = (int*)  alloc((size_t)N_EDGES * 4);
    int*   blkTot = (int*)  alloc(256 * 4);
    float* dinv   = (float*)alloc((size_t)N_NODES * 4);
    unsigned short* W0t = (unsigned short*)alloc((size_t)W0N * IN_F * 2);
    unsigned short* W1t = (unsigned short*)alloc((size_t)W1N * HID_F * 2);
    float* H      = (float*)alloc((size_t)N_NODES * W0N * 4);   // H0, reused as H1
    unsigned short* hbuf = (unsigned short*)alloc((size_t)N_NODES * HID_F * 2);

    const int EB = (N_EDGES + 255) / 256;

    // CSR build
    hipMemsetAsync(deg, 0, (size_t)N_NODES * 4, stream);
    hipMemsetAsync(cursor, 0, (size_t)N_NODES * 4, stream);
    k_count<<<EB, 256, 0, stream>>>(ei, deg);
    k_dinv<<<NB, 256, 0, stream>>>(deg, dinv);
    k_scan1<<<NB, 256, 0, stream>>>(deg, rowPtr, blkTot);
    k_scan2<<<1, 256, 0, stream>>>(blkTot);
    k_scan3<<<NB, 256, 0, stream>>>(deg, blkTot, rowPtr);
    k_fill<<<EB, 256, 0, stream>>>(ei, rowPtr, cursor, colIdx);

    // layer 0: H = x @ [Wl0|Wh0|Wm0]  (bf16 MFMA, A converted on the fly)
    k_packT<<<(W0N * IN_F + 255) / 256, 256, 0, stream>>>(Wl0, Wh0, Wm0, W0t, IN_F, HID_F);
    {
        dim3 grid(W0N / 128, (N_NODES + 127) / 128);
        k_gemm_mfma<true><<<grid, 256, 0, stream>>>(x, W0t, H, N_NODES, W0N, IN_F);
    }
    k_layer0<<<N_NODES, 256, 0, stream>>>(H, rowPtr, colIdx, dinv, al0, ah0, am0, att0, hbuf);

    // layer 1: H1 = h @ [Wl1|Wh1|Wm1]  (A already bf16)
    k_packT<<<(W1N * HID_F + 255) / 256, 256, 0, stream>>>(Wl1, Wh1, Wm1, W1t, HID_F, OUT_F);
    {
        dim3 grid(1, (N_NODES + 127) / 128);
        k_gemm_mfma<false><<<grid, 256, 0, stream>>>(hbuf, W1t, H, N_NODES, W1N, HID_F);
    }
    k_layer1<<<N_NODES, 128, 0, stream>>>(H, rowPtr, colIdx, dinv, al1, ah1, am1, att1, out);
}

// Round 3
// 265.670 us; speedup vs baseline: 2.6960x; 1.7708x over previous
//
#include <hip/hip_runtime.h>
#include <math.h>

#define N_NODES 50000
#define N_EDGES 800000
#define IN_F    256
#define HID_F   128
#define OUT_F   40
#define W0N     (3*HID_F)   // 384
#define W1N     (3*OUT_F)   // 120
#define NB      ((N_NODES + 255) / 256)

typedef __attribute__((ext_vector_type(8))) unsigned short ushort8;
typedef __attribute__((ext_vector_type(4))) unsigned short ushort4v;
typedef __attribute__((ext_vector_type(8))) __bf16 bf16x8;
typedef __attribute__((ext_vector_type(4))) float f32x4;

static __device__ __forceinline__ float sigmoidf_(float x) {
    return 1.0f / (1.0f + expf(-x));
}

static __device__ __forceinline__ unsigned short f2bf(float f) {
    unsigned u = __float_as_uint(f);
    u += 0x7FFFu + ((u >> 16) & 1u);
    return (unsigned short)(u >> 16);
}

static __device__ __forceinline__ float bflo(unsigned u) { return __uint_as_float(u << 16); }
static __device__ __forceinline__ float bfhi(unsigned u) { return __uint_as_float(u & 0xffff0000u); }

// ---------------- CSR build ----------------

__global__ void k_count(const int* __restrict__ ei, int* __restrict__ deg) {
    int e = blockIdx.x * blockDim.x + threadIdx.x;
    if (e < N_EDGES) atomicAdd(&deg[ei[e]], 1);
}

__global__ void k_dinv(const int* __restrict__ deg, float* __restrict__ dinv) {
    int i = blockIdx.x * blockDim.x + threadIdx.x;
    if (i < N_NODES) dinv[i] = 1.0f / (1.0f + (float)deg[i]);
}

__global__ void k_scan1(const int* __restrict__ deg, int* __restrict__ rowPtr,
                        int* __restrict__ blkTot) {
    __shared__ int s[256];
    int t = threadIdx.x;
    int gid = blockIdx.x * 256 + t;
    int v = (gid < N_NODES) ? deg[gid] : 0;
    s[t] = v; __syncthreads();
    for (int d = 1; d < 256; d <<= 1) {
        int x = (t >= d) ? s[t - d] : 0;
        __syncthreads();
        s[t] += x;
        __syncthreads();
    }
    if (gid < N_NODES) rowPtr[gid] = s[t];
    if (t == 255) blkTot[blockIdx.x] = s[255];
}

__global__ void k_scan2(int* __restrict__ blk) {
    __shared__ int s[256];
    int t = threadIdx.x;
    int v = (t < NB) ? blk[t] : 0;
    s[t] = v; __syncthreads();
    for (int d = 1; d < 256; d <<= 1) {
        int x = (t >= d) ? s[t - d] : 0;
        __syncthreads();
        s[t] += x;
        __syncthreads();
    }
    if (t < NB) blk[t] = s[t] - v;
}

__global__ void k_scan3(const int* __restrict__ deg, const int* __restrict__ blkOff,
                        int* __restrict__ rowPtr) {
    int t = threadIdx.x;
    int gid = blockIdx.x * 256 + t;
    if (gid < N_NODES) rowPtr[gid] += blkOff[blockIdx.x] - deg[gid];
    if (gid == 0) rowPtr[N_NODES] = N_EDGES;
}

__global__ void k_fill(const int* __restrict__ ei, const int* __restrict__ rowPtr,
                       int* __restrict__ cursor, int* __restrict__ colIdx) {
    int e = blockIdx.x * blockDim.x + threadIdx.x;
    if (e < N_EDGES) {
        int r = ei[e];
        int c = ei[N_EDGES + e];
        int pos = rowPtr[r] + atomicAdd(&cursor[r], 1);
        colIdx[pos] = c;
    }
}

// ---------------- weight pack: Bt[n][k] = W[k][n], bf16, n = [Wl|Wh|Wm] ----------------

__global__ void k_packT(const float* __restrict__ Wl, const float* __restrict__ Wh,
                        const float* __restrict__ Wm, unsigned short* __restrict__ Bt,
                        int K, int sub) {
    int i = blockIdx.x * blockDim.x + threadIdx.x;
    int cols = 3 * sub;
    if (i < K * cols) {
        int n = i / K, k = i % K;
        float v;
        if (n < sub)            v = Wl[k * sub + n];
        else if (n < 2 * sub)   v = Wh[k * sub + (n - sub)];
        else                    v = Wm[k * sub + (n - 2 * sub)];
        Bt[i] = f2bf(v);
    }
}

// ---------------- bf16 MFMA GEMM: split bf16 C-write ----------------
// tile 128x128, BK=32, 4 waves (2x2), each wave 64x64 = 4x4 frags of 16x16x32
// C cols [0,nsplit) -> C0 (ld0), cols [nsplit,N) -> C1 (ld1), both bf16

#define BKP 40   // 32 + 8 pad

template<bool CVT_A>
__global__ __launch_bounds__(256) void k_gemm_mfma(
        const void* __restrict__ Av, const unsigned short* __restrict__ Bt,
        unsigned short* __restrict__ C0, int ld0,
        unsigned short* __restrict__ C1, int ld1, int nsplit,
        int M, int N, int K) {
    __shared__ unsigned short As[128 * BKP];
    __shared__ unsigned short Bs[128 * BKP];
    int tid  = threadIdx.x;
    int lane = tid & 63, wid = tid >> 6;
    int wr = wid >> 1, wc = wid & 1;
    int bm = blockIdx.y * 128, bn = blockIdx.x * 128;

    int srow = tid >> 1;
    int scol = (tid & 1) * 16;

    int garow = min(bm + srow, M - 1);
    int gbrow = min(bn + srow, N - 1);

    const float*          Af = (const float*)Av;
    const unsigned short* Ab = (const unsigned short*)Av;

    f32x4 acc[4][4];
#pragma unroll
    for (int m = 0; m < 4; ++m)
#pragma unroll
        for (int n = 0; n < 4; ++n)
            acc[m][n] = (f32x4)(0.0f);

    int kg = (lane >> 4) * 8;
    int rA = wr * 64 + (lane & 15);
    int rB = wc * 64 + (lane & 15);

    for (int k0 = 0; k0 < K; k0 += 32) {
        if (CVT_A) {
            const float* src = Af + (size_t)garow * K + k0 + scol;
            float4 f0 = *(const float4*)(src);
            float4 f1 = *(const float4*)(src + 4);
            float4 f2 = *(const float4*)(src + 8);
            float4 f3 = *(const float4*)(src + 12);
            ushort8 u0, u1;
            u0[0]=f2bf(f0.x); u0[1]=f2bf(f0.y); u0[2]=f2bf(f0.z); u0[3]=f2bf(f0.w);
            u0[4]=f2bf(f1.x); u0[5]=f2bf(f1.y); u0[6]=f2bf(f1.z); u0[7]=f2bf(f1.w);
            u1[0]=f2bf(f2.x); u1[1]=f2bf(f2.y); u1[2]=f2bf(f2.z); u1[3]=f2bf(f2.w);
            u1[4]=f2bf(f3.x); u1[5]=f2bf(f3.y); u1[6]=f2bf(f3.z); u1[7]=f2bf(f3.w);
            *(ushort8*)&As[srow * BKP + scol]     = u0;
            *(ushort8*)&As[srow * BKP + scol + 8] = u1;
        } else {
            const unsigned short* src = Ab + (size_t)garow * K + k0 + scol;
            *(ushort8*)&As[srow * BKP + scol]     = *(const ushort8*)(src);
            *(ushort8*)&As[srow * BKP + scol + 8] = *(const ushort8*)(src + 8);
        }
        {
            const unsigned short* src = Bt + (size_t)gbrow * K + k0 + scol;
            *(ushort8*)&Bs[srow * BKP + scol]     = *(const ushort8*)(src);
            *(ushort8*)&Bs[srow * BKP + scol + 8] = *(const ushort8*)(src + 8);
        }
        __syncthreads();

        bf16x8 a[4], b[4];
#pragma unroll
        for (int m = 0; m < 4; ++m)
            a[m] = __builtin_bit_cast(bf16x8, *(const ushort8*)&As[(rA + m * 16) * BKP + kg]);
#pragma unroll
        for (int n = 0; n < 4; ++n)
            b[n] = __builtin_bit_cast(bf16x8, *(const ushort8*)&Bs[(rB + n * 16) * BKP + kg]);
#pragma unroll
        for (int m = 0; m < 4; ++m)
#pragma unroll
            for (int n = 0; n < 4; ++n)
                acc[m][n] = __builtin_amdgcn_mfma_f32_16x16x32_bf16(a[m], b[n], acc[m][n], 0, 0, 0);
        __syncthreads();
    }

    int col  = lane & 15;
    int rsub = (lane >> 4) * 4;
#pragma unroll
    for (int m = 0; m < 4; ++m) {
        int gm0 = bm + wr * 64 + m * 16 + rsub;
#pragma unroll
        for (int n = 0; n < 4; ++n) {
            int gn = bn + wc * 64 + n * 16 + col;
            if (gn >= N) continue;
#pragma unroll
            for (int j = 0; j < 4; ++j) {
                int gm = gm0 + j;
                if (gm >= M) continue;
                unsigned short b = f2bf(acc[m][n][j]);
                if (gn < nsplit) C0[(size_t)gm * ld0 + gn] = b;
                else             C1[(size_t)gm * ld1 + (gn - nsplit)] = b;
            }
        }
    }
}

// ---------------- layer 0: wave-per-node aggregate + ACM epilogue ----------------
// Hg[i][c] bf16, c<128: hl feat c; c>=128: hh feat c-128.  Hm[i][f]: hm feat f.
// lane handles combined feats c = lane*4..lane*4+3.

__global__ __launch_bounds__(256) void k_layer0(
        const unsigned short* __restrict__ Hg, const unsigned short* __restrict__ Hm,
        const int* __restrict__ rowPtr, const int* __restrict__ colIdx,
        const float* __restrict__ dinv,
        const float* __restrict__ al, const float* __restrict__ ah,
        const float* __restrict__ am, const float* __restrict__ att,
        unsigned short* __restrict__ hout) {
    int lane = threadIdx.x & 63;
    int i = blockIdx.x * 4 + (threadIdx.x >> 6);

    int p0 = rowPtr[i], p1 = rowPtr[i + 1];
    float a0 = 0.f, a1 = 0.f, a2 = 0.f, a3 = 0.f;
    int off = lane * 4;
    int p = p0;
    for (; p + 3 < p1; p += 4) {
        int j0 = colIdx[p], j1 = colIdx[p+1], j2 = colIdx[p+2], j3 = colIdx[p+3];
        uint2 v0 = *(const uint2*)(Hg + (size_t)j0 * 256 + off);
        uint2 v1 = *(const uint2*)(Hg + (size_t)j1 * 256 + off);
        uint2 v2 = *(const uint2*)(Hg + (size_t)j2 * 256 + off);
        uint2 v3 = *(const uint2*)(Hg + (size_t)j3 * 256 + off);
        a0 += bflo(v0.x) + bflo(v1.x) + bflo(v2.x) + bflo(v3.x);
        a1 += bfhi(v0.x) + bfhi(v1.x) + bfhi(v2.x) + bfhi(v3.x);
        a2 += bflo(v0.y) + bflo(v1.y) + bflo(v2.y) + bflo(v3.y);
        a3 += bfhi(v0.y) + bfhi(v1.y) + bfhi(v2.y) + bfhi(v3.y);
    }
    for (; p < p1; ++p) {
        int j = colIdx[p];
        uint2 v = *(const uint2*)(Hg + (size_t)j * 256 + off);
        a0 += bflo(v.x); a1 += bfhi(v.x); a2 += bflo(v.y); a3 += bfhi(v.y);
    }

    uint2 sv = *(const uint2*)(Hg + (size_t)i * 256 + off);
    float s0 = bflo(sv.x), s1 = bfhi(sv.x), s2 = bflo(sv.y), s3 = bfhi(sv.y);
    float di = dinv[i];
    float l0 = di * (s0 + a0), l1 = di * (s1 + a1);
    float l2 = di * (s2 + a2), l3 = di * (s3 + a3);

    // lanes <32: ol, om; lanes >=32: oh
    float ol0 = fmaxf(l0, 0.f), ol1 = fmaxf(l1, 0.f);
    float ol2 = fmaxf(l2, 0.f), ol3 = fmaxf(l3, 0.f);
    float oh0 = fmaxf(s0 - l0, 0.f), oh1 = fmaxf(s1 - l1, 0.f);
    float oh2 = fmaxf(s2 - l2, 0.f), oh3 = fmaxf(s3 - l3, 0.f);

    float om0 = 0.f, om1 = 0.f, om2 = 0.f, om3 = 0.f;
    float prA, prM = 0.f;
    if (lane < 32) {
        uint2 hv = *(const uint2*)(Hm + (size_t)i * 128 + off);
        om0 = fmaxf(bflo(hv.x), 0.f); om1 = fmaxf(bfhi(hv.x), 0.f);
        om2 = fmaxf(bflo(hv.y), 0.f); om3 = fmaxf(bfhi(hv.y), 0.f);
        float4 alv = *(const float4*)(al + off);
        float4 amv = *(const float4*)(am + off);
        prA = ol0 * alv.x + ol1 * alv.y + ol2 * alv.z + ol3 * alv.w;
        prM = om0 * amv.x + om1 * amv.y + om2 * amv.z + om3 * amv.w;
    } else {
        const float* ahp = ah + (off - 128);
        float4 ahv = *(const float4*)ahp;
        prA = oh0 * ahv.x + oh1 * ahv.y + oh2 * ahv.z + oh3 * ahv.w;
    }

    // reduce within each 32-lane half
#pragma unroll
    for (int d = 1; d < 32; d <<= 1) prA += __shfl_xor(prA, d);
#pragma unroll
    for (int d = 1; d < 32; d <<= 1) prM += __shfl_xor(prM, d);
    float g0 = __shfl(prA, 0);
    float g1 = __shfl(prA, 32);
    float g2 = __shfl(prM, 0);

    float sg0 = sigmoidf_(g0), sg1 = sigmoidf_(g1), sg2 = sigmoidf_(g2);
    const float inv3 = (1.0f / 3.0f);
    float e0 = (sg0 * att[0] + sg1 * att[3] + sg2 * att[6]) * inv3;
    float e1 = (sg0 * att[1] + sg1 * att[4] + sg2 * att[7]) * inv3;
    float e2 = (sg0 * att[2] + sg1 * att[5] + sg2 * att[8]) * inv3;
    float mx = fmaxf(e0, fmaxf(e1, e2));
    float x0 = expf(e0 - mx), x1 = expf(e1 - mx), x2 = expf(e2 - mx);
    float inv = 1.0f / (x0 + x1 + x2);
    float c0 = 3.0f * inv * x0, c1 = 3.0f * inv * x1, c2 = 3.0f * inv * x2;

    // bring oh (held by lane+32) down to lanes <32
    int src = lane | 32;
    float th0 = __shfl(oh0, src), th1 = __shfl(oh1, src);
    float th2 = __shfl(oh2, src), th3 = __shfl(oh3, src);

    if (lane < 32) {
        ushort4v o;
        o[0] = f2bf(c0 * ol0 + c1 * th0 + c2 * om0);
        o[1] = f2bf(c0 * ol1 + c1 * th1 + c2 * om1);
        o[2] = f2bf(c0 * ol2 + c1 * th2 + c2 * om2);
        o[3] = f2bf(c0 * ol3 + c1 * th3 + c2 * om3);
        *(ushort4v*)&hout[(size_t)i * 128 + off] = o;
    }
}

// ---------------- layer 1: wave-per-node aggregate + ACM epilogue ----------------
// H1g[i][c] bf16, c<40: hl; c>=40: hh (80 cols). H1m[i][f]: hm (40 cols).
// lanes 0..39: combined feats c = 2*lane, 2*lane+1.

__global__ __launch_bounds__(256) void k_layer1(
        const unsigned short* __restrict__ H1g, const unsigned short* __restrict__ H1m,
        const int* __restrict__ rowPtr, const int* __restrict__ colIdx,
        const float* __restrict__ dinv,
        const float* __restrict__ al, const float* __restrict__ ah,
        const float* __restrict__ am, const float* __restrict__ att,
        float* __restrict__ out) {
    int lane = threadIdx.x & 63;
    int i = blockIdx.x * 4 + (threadIdx.x >> 6);

    int p0 = rowPtr[i], p1 = rowPtr[i + 1];
    float a0 = 0.f, a1 = 0.f;
    int off = lane * 2;
    bool active = lane < 40;
    int p = p0;
    if (active) {
        for (; p + 3 < p1; p += 4) {
            int j0 = colIdx[p], j1 = colIdx[p+1], j2 = colIdx[p+2], j3 = colIdx[p+3];
            unsigned v0 = *(const unsigned*)(H1g + (size_t)j0 * 80 + off);
            unsigned v1 = *(const unsigned*)(H1g + (size_t)j1 * 80 + off);
            unsigned v2 = *(const unsigned*)(H1g + (size_t)j2 * 80 + off);
            unsigned v3 = *(const unsigned*)(H1g + (size_t)j3 * 80 + off);
            a0 += bflo(v0) + bflo(v1) + bflo(v2) + bflo(v3);
            a1 += bfhi(v0) + bfhi(v1) + bfhi(v2) + bfhi(v3);
        }
        for (; p < p1; ++p) {
            int j = colIdx[p];
            unsigned v = *(const unsigned*)(H1g + (size_t)j * 80 + off);
            a0 += bflo(v); a1 += bfhi(v);
        }
    }

    float s0 = 0.f, s1 = 0.f;
    if (active) {
        unsigned sv = *(const unsigned*)(H1g + (size_t)i * 80 + off);
        s0 = bflo(sv); s1 = bfhi(sv);
    }
    float di = dinv[i];
    float l0 = di * (s0 + a0), l1 = di * (s1 + a1);

    float ol0 = fmaxf(l0, 0.f), ol1 = fmaxf(l1, 0.f);
    float oh0 = fmaxf(s0 - l0, 0.f), oh1 = fmaxf(s1 - l1, 0.f);

    float om0 = 0.f, om1 = 0.f;
    float r0 = 0.f, r1 = 0.f, r2 = 0.f;
    if (lane < 20) {
        unsigned hv = *(const unsigned*)(H1m + (size_t)i * 40 + off);
        om0 = fmaxf(bflo(hv), 0.f); om1 = fmaxf(bfhi(hv), 0.f);
        float2 alv = *(const float2*)(al + off);
        float2 amv = *(const float2*)(am + off);
        r0 = ol0 * alv.x + ol1 * alv.y;
        r2 = om0 * amv.x + om1 * amv.y;
    } else if (lane < 40) {
        float2 ahv = *(const float2*)(ah + (off - 40));
        r1 = oh0 * ahv.x + oh1 * ahv.y;
    }

#pragma unroll
    for (int d = 1; d < 64; d <<= 1) r0 += __shfl_xor(r0, d);
#pragma unroll
    for (int d = 1; d < 64; d <<= 1) r1 += __shfl_xor(r1, d);
#pragma unroll
    for (int d = 1; d < 64; d <<= 1) r2 += __shfl_xor(r2, d);

    float sg0 = sigmoidf_(r0), sg1 = sigmoidf_(r1), sg2 = sigmoidf_(r2);
    const float inv3 = (1.0f / 3.0f);
    float e0 = (sg0 * att[0] + sg1 * att[3] + sg2 * att[6]) * inv3;
    float e1 = (sg0 * att[1] + sg1 * att[4] + sg2 * att[7]) * inv3;
    float e2 = (sg0 * att[2] + sg1 * att[5] + sg2 * att[8]) * inv3;
    float mx = fmaxf(e0, fmaxf(e1, e2));
    float x0 = expf(e0 - mx), x1 = expf(e1 - mx), x2 = expf(e2 - mx);
    float inv = 1.0f / (x0 + x1 + x2);
    float c0 = 3.0f * inv * x0, c1 = 3.0f * inv * x1, c2 = 3.0f * inv * x2;

    int src = (lane + 20) & 63;
    float th0 = __shfl(oh0, src), th1 = __shfl(oh1, src);

    if (lane < 20) {
        float2 o;
        o.x = c0 * ol0 + c1 * th0 + c2 * om0;
        o.y = c0 * ol1 + c1 * th1 + c2 * om1;
        *(float2*)&out[(size_t)i * 40 + off] = o;
    }
}

// ---------------- launch ----------------

extern "C" void kernel_launch(void* const* d_in, const int* in_sizes, int n_in,
                              void* d_out, int out_size, void* d_ws, size_t ws_size,
                              hipStream_t stream) {
    const float* x    = (const float*)d_in[0];
    const int*   ei   = (const int*)d_in[1];
    const float* Wl0  = (const float*)d_in[2];
    const float* Wh0  = (const float*)d_in[3];
    const float* Wm0  = (const float*)d_in[4];
    const float* al0  = (const float*)d_in[5];
    const float* ah0  = (const float*)d_in[6];
    const float* am0  = (const float*)d_in[7];
    const float* att0 = (const float*)d_in[8];
    const float* Wl1  = (const float*)d_in[9];
    const float* Wh1  = (const float*)d_in[10];
    const float* Wm1  = (const float*)d_in[11];
    const float* al1  = (const float*)d_in[12];
    const float* ah1  = (const float*)d_in[13];
    const float* am1  = (const float*)d_in[14];
    const float* att1 = (const float*)d_in[15];
    float* out = (float*)d_out;

    char* ws = (char*)d_ws;
    size_t off = 0;
    auto alloc = [&](size_t bytes) -> char* {
        char* p = ws + off;
        off += (bytes + 255) & ~(size_t)255;
        return p;
    };
    int*   deg    = (int*)  alloc((size_t)N_NODES * 4);
    int*   cursor = (int*)  alloc((size_t)N_NODES * 4);
    int*   rowPtr = (int*)  alloc((size_t)(N_NODES + 1) * 4);
    int*   colIdx = (int*)  alloc((size_t)N_EDGES * 4);
    int*   blkTot = (int*)  alloc(256 * 4);
    float* dinv   = (float*)alloc((size_t)N_NODES * 4);
    unsigned short* W0t  = (unsigned short*)alloc((size_t)W0N * IN_F * 2);
    unsigned short* W1t  = (unsigned short*)alloc((size_t)W1N * HID_F * 2);
    unsigned short* Hg   = (unsigned short*)alloc((size_t)N_NODES * 256 * 2);
    unsigned short* Hm   = (unsigned short*)alloc((size_t)N_NODES * 128 * 2);
    unsigned short* H1g  = (unsigned short*)alloc((size_t)N_NODES * 80 * 2);
    unsigned short* H1m  = (unsigned short*)alloc((size_t)N_NODES * 40 * 2);
    unsigned short* hbuf = (unsigned short*)alloc((size_t)N_NODES * HID_F * 2);

    const int EB = (N_EDGES + 255) / 256;

    // CSR build
    hipMemsetAsync(deg, 0, (size_t)N_NODES * 4, stream);
    hipMemsetAsync(cursor, 0, (size_t)N_NODES * 4, stream);
    k_count<<<EB, 256, 0, stream>>>(ei, deg);
    k_dinv<<<NB, 256, 0, stream>>>(deg, dinv);
    k_scan1<<<NB, 256, 0, stream>>>(deg, rowPtr, blkTot);
    k_scan2<<<1, 256, 0, stream>>>(blkTot);
    k_scan3<<<NB, 256, 0, stream>>>(deg, blkTot, rowPtr);
    k_fill<<<EB, 256, 0, stream>>>(ei, rowPtr, cursor, colIdx);

    // layer 0
    k_packT<<<(W0N * IN_F + 255) / 256, 256, 0, stream>>>(Wl0, Wh0, Wm0, W0t, IN_F, HID_F);
    {
        dim3 grid(W0N / 128, (N_NODES + 127) / 128);
        k_gemm_mfma<true><<<grid, 256, 0, stream>>>(x, W0t, Hg, 256, Hm, 128, 256,
                                                    N_NODES, W0N, IN_F);
    }
    k_layer0<<<N_NODES / 4, 256, 0, stream>>>(Hg, Hm, rowPtr, colIdx, dinv,
                                              al0, ah0, am0, att0, hbuf);

    // layer 1
    k_packT<<<(W1N * HID_F + 255) / 256, 256, 0, stream>>>(Wl1, Wh1, Wm1, W1t, HID_F, OUT_F);
    {
        dim3 grid(1, (N_NODES + 127) / 128);
        k_gemm_mfma<false><<<grid, 256, 0, stream>>>(hbuf, W1t, H1g, 80, H1m, 40, 80,
                                                     N_NODES, W1N, HID_F);
    }
    k_layer1<<<N_NODES / 4, 256, 0, stream>>>(H1g, H1m, rowPtr, colIdx, dinv,
                                              al1, ah1, am1, att1, out);
}

// Round 4
// 237.100 us; speedup vs baseline: 3.0208x; 1.1205x over previous
//
#include <hip/hip_runtime.h>
#include <math.h>

#define N_NODES 50000
#define N_EDGES 800000
#define IN_F    256
#define HID_F   128
#define OUT_F   40
#define W0N     (3*HID_F)   // 384
#define W1N     (3*OUT_F)   // 120
#define NB      ((N_NODES + 255) / 256)

// k_prep block ranges
#define XB   6250                        // x convert: 12.8M elems / (256*8)
#define P0B  ((IN_F * W0N) / 256)        // 384
#define P1B  ((HID_F * W1N) / 256)       // 60
#define CB0  (XB + P0B + P1B)            // 6694
#define CNTB ((N_EDGES + 255) / 256)     // 3125
#define PREPB (CB0 + CNTB)               // 9819

typedef __attribute__((ext_vector_type(8))) unsigned short ushort8;
typedef __attribute__((ext_vector_type(4))) unsigned short ushort4v;
typedef __attribute__((ext_vector_type(8))) __bf16 bf16x8;
typedef __attribute__((ext_vector_type(4))) float f32x4;

static __device__ __forceinline__ float sigmoidf_(float x) {
    return 1.0f / (1.0f + expf(-x));
}

static __device__ __forceinline__ unsigned short f2bf(float f) {
    unsigned u = __float_as_uint(f);
    u += 0x7FFFu + ((u >> 16) & 1u);
    return (unsigned short)(u >> 16);
}

static __device__ __forceinline__ float bflo(unsigned u) { return __uint_as_float(u << 16); }
static __device__ __forceinline__ float bfhi(unsigned u) { return __uint_as_float(u & 0xffff0000u); }

// ---------------- fused prep: x->bf16 | pack W0^T | pack W1^T | count ----------------

static __device__ __forceinline__ void pack_body(const float* __restrict__ Wl,
                                                 const float* __restrict__ Wh,
                                                 const float* __restrict__ Wm,
                                                 unsigned short* __restrict__ Bt,
                                                 int K, int sub, int i) {
    int n = i / K, k = i % K;
    float v;
    if (n < sub)            v = Wl[k * sub + n];
    else if (n < 2 * sub)   v = Wh[k * sub + (n - sub)];
    else                    v = Wm[k * sub + (n - 2 * sub)];
    Bt[i] = f2bf(v);
}

__global__ __launch_bounds__(256) void k_prep(
        const float* __restrict__ x, unsigned short* __restrict__ xb,
        const float* __restrict__ Wl0, const float* __restrict__ Wh0,
        const float* __restrict__ Wm0, unsigned short* __restrict__ W0t,
        const float* __restrict__ Wl1, const float* __restrict__ Wh1,
        const float* __restrict__ Wm1, unsigned short* __restrict__ W1t,
        const int* __restrict__ ei, int* __restrict__ deg) {
    int b = blockIdx.x, t = threadIdx.x;
    if (b < XB) {
        size_t idx = (size_t)b * 2048 + t * 8;
        float4 f0 = *(const float4*)(x + idx);
        float4 f1 = *(const float4*)(x + idx + 4);
        ushort8 u;
        u[0]=f2bf(f0.x); u[1]=f2bf(f0.y); u[2]=f2bf(f0.z); u[3]=f2bf(f0.w);
        u[4]=f2bf(f1.x); u[5]=f2bf(f1.y); u[6]=f2bf(f1.z); u[7]=f2bf(f1.w);
        *(ushort8*)(xb + idx) = u;
    } else if (b < XB + P0B) {
        int i = (b - XB) * 256 + t;
        pack_body(Wl0, Wh0, Wm0, W0t, IN_F, HID_F, i);
    } else if (b < CB0) {
        int i = (b - XB - P0B) * 256 + t;
        pack_body(Wl1, Wh1, Wm1, W1t, HID_F, OUT_F, i);
    } else {
        int e = (b - CB0) * 256 + t;
        if (e < N_EDGES) atomicAdd(&deg[ei[e]], 1);
    }
}

// ---------------- CSR scan ----------------

__global__ void k_scan1(const int* __restrict__ deg, int* __restrict__ rowPtr,
                        int* __restrict__ blkTot, float* __restrict__ dinv) {
    __shared__ int s[256];
    int t = threadIdx.x;
    int gid = blockIdx.x * 256 + t;
    int v = (gid < N_NODES) ? deg[gid] : 0;
    if (gid < N_NODES) dinv[gid] = 1.0f / (1.0f + (float)v);
    s[t] = v; __syncthreads();
    for (int d = 1; d < 256; d <<= 1) {
        int x = (t >= d) ? s[t - d] : 0;
        __syncthreads();
        s[t] += x;
        __syncthreads();
    }
    if (gid < N_NODES) rowPtr[gid] = s[t];
    if (t == 255) blkTot[blockIdx.x] = s[255];
}

__global__ void k_scan2(int* __restrict__ blk) {
    __shared__ int s[256];
    int t = threadIdx.x;
    int v = (t < NB) ? blk[t] : 0;
    s[t] = v; __syncthreads();
    for (int d = 1; d < 256; d <<= 1) {
        int x = (t >= d) ? s[t - d] : 0;
        __syncthreads();
        s[t] += x;
        __syncthreads();
    }
    if (t < NB) blk[t] = s[t] - v;
}

__global__ void k_scan3(const int* __restrict__ deg, const int* __restrict__ blkOff,
                        int* __restrict__ rowPtr) {
    int t = threadIdx.x;
    int gid = blockIdx.x * 256 + t;
    if (gid < N_NODES) rowPtr[gid] += blkOff[blockIdx.x] - deg[gid];
    if (gid == 0) rowPtr[N_NODES] = N_EDGES;
}

// ---------------- bf16 MFMA GEMM (A bf16) + optional fused CSR-fill ----------------
// tile 128x128, BK=32, 4 waves (2x2); C cols [0,nsplit)->C0, rest->C1, bf16.
// blocks with blockIdx.x >= nxt run the CSR fill instead.

#define BKP 40   // 32 + 8 pad

__global__ __launch_bounds__(256) void k_gemm_fill(
        const unsigned short* __restrict__ A, const unsigned short* __restrict__ Bt,
        unsigned short* __restrict__ C0, int ld0,
        unsigned short* __restrict__ C1, int ld1, int nsplit,
        int M, int N, int K, int nxt,
        const int* __restrict__ ei, const int* __restrict__ rowPtr,
        int* __restrict__ cursor, int* __restrict__ colIdx) {
    __shared__ unsigned short As[128 * BKP];
    __shared__ unsigned short Bs[128 * BKP];
    int tid  = threadIdx.x;

    if ((int)blockIdx.x >= nxt) {
        int fid = (blockIdx.x - nxt) * gridDim.y + blockIdx.y;
        int e = fid * 256 + tid;
        if (e < N_EDGES) {
            int r = ei[e];
            int c = ei[N_EDGES + e];
            int pos = rowPtr[r] + atomicAdd(&cursor[r], 1);
            colIdx[pos] = c;
        }
        return;
    }

    int lane = tid & 63, wid = tid >> 6;
    int wr = wid >> 1, wc = wid & 1;
    int bm = blockIdx.y * 128, bn = blockIdx.x * 128;

    int srow = tid >> 1;
    int scol = (tid & 1) * 16;

    int garow = min(bm + srow, M - 1);
    int gbrow = min(bn + srow, N - 1);

    f32x4 acc[4][4];
#pragma unroll
    for (int m = 0; m < 4; ++m)
#pragma unroll
        for (int n = 0; n < 4; ++n)
            acc[m][n] = (f32x4)(0.0f);

    int kg = (lane >> 4) * 8;
    int rA = wr * 64 + (lane & 15);
    int rB = wc * 64 + (lane & 15);

    for (int k0 = 0; k0 < K; k0 += 32) {
        {
            const unsigned short* src = A + (size_t)garow * K + k0 + scol;
            *(ushort8*)&As[srow * BKP + scol]     = *(const ushort8*)(src);
            *(ushort8*)&As[srow * BKP + scol + 8] = *(const ushort8*)(src + 8);
        }
        {
            const unsigned short* src = Bt + (size_t)gbrow * K + k0 + scol;
            *(ushort8*)&Bs[srow * BKP + scol]     = *(const ushort8*)(src);
            *(ushort8*)&Bs[srow * BKP + scol + 8] = *(const ushort8*)(src + 8);
        }
        __syncthreads();

        bf16x8 a[4], b[4];
#pragma unroll
        for (int m = 0; m < 4; ++m)
            a[m] = __builtin_bit_cast(bf16x8, *(const ushort8*)&As[(rA + m * 16) * BKP + kg]);
#pragma unroll
        for (int n = 0; n < 4; ++n)
            b[n] = __builtin_bit_cast(bf16x8, *(const ushort8*)&Bs[(rB + n * 16) * BKP + kg]);
#pragma unroll
        for (int m = 0; m < 4; ++m)
#pragma unroll
            for (int n = 0; n < 4; ++n)
                acc[m][n] = __builtin_amdgcn_mfma_f32_16x16x32_bf16(a[m], b[n], acc[m][n], 0, 0, 0);
        __syncthreads();
    }

    int col  = lane & 15;
    int rsub = (lane >> 4) * 4;
#pragma unroll
    for (int m = 0; m < 4; ++m) {
        int gm0 = bm + wr * 64 + m * 16 + rsub;
#pragma unroll
        for (int n = 0; n < 4; ++n) {
            int gn = bn + wc * 64 + n * 16 + col;
            if (gn >= N) continue;
#pragma unroll
            for (int j = 0; j < 4; ++j) {
                int gm = gm0 + j;
                if (gm >= M) continue;
                unsigned short b = f2bf(acc[m][n][j]);
                if (gn < nsplit) C0[(size_t)gm * ld0 + gn] = b;
                else             C1[(size_t)gm * ld1 + (gn - nsplit)] = b;
            }
        }
    }
}

// ---------------- layer 0: wave-per-node aggregate + ACM epilogue ----------------
// Hg[i][c] bf16: c<128 hl, c>=128 hh. Hm[i][f]: hm. lane covers feats lane*4..+3.

__global__ __launch_bounds__(256) void k_layer0(
        const unsigned short* __restrict__ Hg, const unsigned short* __restrict__ Hm,
        const int* __restrict__ rowPtr, const int* __restrict__ colIdx,
        const float* __restrict__ dinv,
        const float* __restrict__ al, const float* __restrict__ ah,
        const float* __restrict__ am, const float* __restrict__ att,
        unsigned short* __restrict__ hout) {
    int lane = threadIdx.x & 63;
    int i = blockIdx.x * 4 + (threadIdx.x >> 6);

    int p0 = rowPtr[i], p1 = rowPtr[i + 1];
    float a0 = 0.f, a1 = 0.f, a2 = 0.f, a3 = 0.f;
    int off = lane * 4;
    int p = p0;
    for (; p + 7 < p1; p += 8) {
        int j[8];
#pragma unroll
        for (int q = 0; q < 8; ++q) j[q] = colIdx[p + q];
        uint2 v[8];
#pragma unroll
        for (int q = 0; q < 8; ++q) v[q] = *(const uint2*)(Hg + (size_t)j[q] * 256 + off);
#pragma unroll
        for (int q = 0; q < 8; ++q) {
            a0 += bflo(v[q].x); a1 += bfhi(v[q].x);
            a2 += bflo(v[q].y); a3 += bfhi(v[q].y);
        }
    }
    for (; p < p1; ++p) {
        int j = colIdx[p];
        uint2 v = *(const uint2*)(Hg + (size_t)j * 256 + off);
        a0 += bflo(v.x); a1 += bfhi(v.x); a2 += bflo(v.y); a3 += bfhi(v.y);
    }

    uint2 sv = *(const uint2*)(Hg + (size_t)i * 256 + off);
    float s0 = bflo(sv.x), s1 = bfhi(sv.x), s2 = bflo(sv.y), s3 = bfhi(sv.y);
    float di = dinv[i];
    float l0 = di * (s0 + a0), l1 = di * (s1 + a1);
    float l2 = di * (s2 + a2), l3 = di * (s3 + a3);

    float ol0 = fmaxf(l0, 0.f), ol1 = fmaxf(l1, 0.f);
    float ol2 = fmaxf(l2, 0.f), ol3 = fmaxf(l3, 0.f);
    float oh0 = fmaxf(s0 - l0, 0.f), oh1 = fmaxf(s1 - l1, 0.f);
    float oh2 = fmaxf(s2 - l2, 0.f), oh3 = fmaxf(s3 - l3, 0.f);

    float om0 = 0.f, om1 = 0.f, om2 = 0.f, om3 = 0.f;
    float prA, prM = 0.f;
    if (lane < 32) {
        uint2 hv = *(const uint2*)(Hm + (size_t)i * 128 + off);
        om0 = fmaxf(bflo(hv.x), 0.f); om1 = fmaxf(bfhi(hv.x), 0.f);
        om2 = fmaxf(bflo(hv.y), 0.f); om3 = fmaxf(bfhi(hv.y), 0.f);
        float4 alv = *(const float4*)(al + off);
        float4 amv = *(const float4*)(am + off);
        prA = ol0 * alv.x + ol1 * alv.y + ol2 * alv.z + ol3 * alv.w;
        prM = om0 * amv.x + om1 * amv.y + om2 * amv.z + om3 * amv.w;
    } else {
        const float* ahp = ah + (off - 128);
        float4 ahv = *(const float4*)ahp;
        prA = oh0 * ahv.x + oh1 * ahv.y + oh2 * ahv.z + oh3 * ahv.w;
    }

#pragma unroll
    for (int d = 1; d < 32; d <<= 1) prA += __shfl_xor(prA, d);
#pragma unroll
    for (int d = 1; d < 32; d <<= 1) prM += __shfl_xor(prM, d);
    float g0 = __shfl(prA, 0);
    float g1 = __shfl(prA, 32);
    float g2 = __shfl(prM, 0);

    float sg0 = sigmoidf_(g0), sg1 = sigmoidf_(g1), sg2 = sigmoidf_(g2);
    const float inv3 = (1.0f / 3.0f);
    float e0 = (sg0 * att[0] + sg1 * att[3] + sg2 * att[6]) * inv3;
    float e1 = (sg0 * att[1] + sg1 * att[4] + sg2 * att[7]) * inv3;
    float e2 = (sg0 * att[2] + sg1 * att[5] + sg2 * att[8]) * inv3;
    float mx = fmaxf(e0, fmaxf(e1, e2));
    float x0 = expf(e0 - mx), x1 = expf(e1 - mx), x2 = expf(e2 - mx);
    float inv = 1.0f / (x0 + x1 + x2);
    float c0 = 3.0f * inv * x0, c1 = 3.0f * inv * x1, c2 = 3.0f * inv * x2;

    int src = lane | 32;
    float th0 = __shfl(oh0, src), th1 = __shfl(oh1, src);
    float th2 = __shfl(oh2, src), th3 = __shfl(oh3, src);

    if (lane < 32) {
        ushort4v o;
        o[0] = f2bf(c0 * ol0 + c1 * th0 + c2 * om0);
        o[1] = f2bf(c0 * ol1 + c1 * th1 + c2 * om1);
        o[2] = f2bf(c0 * ol2 + c1 * th2 + c2 * om2);
        o[3] = f2bf(c0 * ol3 + c1 * th3 + c2 * om3);
        *(ushort4v*)&hout[(size_t)i * 128 + off] = o;
    }
}

// ---------------- layer 1: wave-per-node aggregate + ACM epilogue ----------------
// H1g[i][c] bf16: c<40 hl, c>=40 hh (80 cols). H1m: hm (40). lanes 0..39 active.

__global__ __launch_bounds__(256) void k_layer1(
        const unsigned short* __restrict__ H1g, const unsigned short* __restrict__ H1m,
        const int* __restrict__ rowPtr, const int* __restrict__ colIdx,
        const float* __restrict__ dinv,
        const float* __restrict__ al, const float* __restrict__ ah,
        const float* __restrict__ am, const float* __restrict__ att,
        float* __restrict__ out) {
    int lane = threadIdx.x & 63;
    int i = blockIdx.x * 4 + (threadIdx.x >> 6);

    int p0 = rowPtr[i], p1 = rowPtr[i + 1];
    float a0 = 0.f, a1 = 0.f;
    int off = lane * 2;
    bool active = lane < 40;
    int p = p0;
    if (active) {
        for (; p + 7 < p1; p += 8) {
            int j[8];
#pragma unroll
            for (int q = 0; q < 8; ++q) j[q] = colIdx[p + q];
            unsigned v[8];
#pragma unroll
            for (int q = 0; q < 8; ++q) v[q] = *(const unsigned*)(H1g + (size_t)j[q] * 80 + off);
#pragma unroll
            for (int q = 0; q < 8; ++q) { a0 += bflo(v[q]); a1 += bfhi(v[q]); }
        }
        for (; p < p1; ++p) {
            int j = colIdx[p];
            unsigned v = *(const unsigned*)(H1g + (size_t)j * 80 + off);
            a0 += bflo(v); a1 += bfhi(v);
        }
    }

    float s0 = 0.f, s1 = 0.f;
    if (active) {
        unsigned sv = *(const unsigned*)(H1g + (size_t)i * 80 + off);
        s0 = bflo(sv); s1 = bfhi(sv);
    }
    float di = dinv[i];
    float l0 = di * (s0 + a0), l1 = di * (s1 + a1);

    float ol0 = fmaxf(l0, 0.f), ol1 = fmaxf(l1, 0.f);
    float oh0 = fmaxf(s0 - l0, 0.f), oh1 = fmaxf(s1 - l1, 0.f);

    float om0 = 0.f, om1 = 0.f;
    float r0 = 0.f, r1 = 0.f, r2 = 0.f;
    if (lane < 20) {
        unsigned hv = *(const unsigned*)(H1m + (size_t)i * 40 + off);
        om0 = fmaxf(bflo(hv), 0.f); om1 = fmaxf(bfhi(hv), 0.f);
        float2 alv = *(const float2*)(al + off);
        float2 amv = *(const float2*)(am + off);
        r0 = ol0 * alv.x + ol1 * alv.y;
        r2 = om0 * amv.x + om1 * amv.y;
    } else if (lane < 40) {
        float2 ahv = *(const float2*)(ah + (off - 40));
        r1 = oh0 * ahv.x + oh1 * ahv.y;
    }

#pragma unroll
    for (int d = 1; d < 64; d <<= 1) r0 += __shfl_xor(r0, d);
#pragma unroll
    for (int d = 1; d < 64; d <<= 1) r1 += __shfl_xor(r1, d);
#pragma unroll
    for (int d = 1; d < 64; d <<= 1) r2 += __shfl_xor(r2, d);

    float sg0 = sigmoidf_(r0), sg1 = sigmoidf_(r1), sg2 = sigmoidf_(r2);
    const float inv3 = (1.0f / 3.0f);
    float e0 = (sg0 * att[0] + sg1 * att[3] + sg2 * att[6]) * inv3;
    float e1 = (sg0 * att[1] + sg1 * att[4] + sg2 * att[7]) * inv3;
    float e2 = (sg0 * att[2] + sg1 * att[5] + sg2 * att[8]) * inv3;
    float mx = fmaxf(e0, fmaxf(e1, e2));
    float x0 = expf(e0 - mx), x1 = expf(e1 - mx), x2 = expf(e2 - mx);
    float inv = 1.0f / (x0 + x1 + x2);
    float c0 = 3.0f * inv * x0, c1 = 3.0f * inv * x1, c2 = 3.0f * inv * x2;

    int src = (lane + 20) & 63;
    float th0 = __shfl(oh0, src), th1 = __shfl(oh1, src);

    if (lane < 20) {
        float2 o;
        o.x = c0 * ol0 + c1 * th0 + c2 * om0;
        o.y = c0 * ol1 + c1 * th1 + c2 * om1;
        *(float2*)&out[(size_t)i * 40 + off] = o;
    }
}

// ---------------- launch ----------------

extern "C" void kernel_launch(void* const* d_in, const int* in_sizes, int n_in,
                              void* d_out, int out_size, void* d_ws, size_t ws_size,
                              hipStream_t stream) {
    const float* x    = (const float*)d_in[0];
    const int*   ei   = (const int*)d_in[1];
    const float* Wl0  = (const float*)d_in[2];
    const float* Wh0  = (const float*)d_in[3];
    const float* Wm0  = (const float*)d_in[4];
    const float* al0  = (const float*)d_in[5];
    const float* ah0  = (const float*)d_in[6];
    const float* am0  = (const float*)d_in[7];
    const float* att0 = (const float*)d_in[8];
    const float* Wl1  = (const float*)d_in[9];
    const float* Wh1  = (const float*)d_in[10];
    const float* Wm1  = (const float*)d_in[11];
    const float* al1  = (const float*)d_in[12];
    const float* ah1  = (const float*)d_in[13];
    const float* am1  = (const float*)d_in[14];
    const float* att1 = (const float*)d_in[15];
    float* out = (float*)d_out;

    char* ws = (char*)d_ws;
    size_t off = 0;
    auto alloc = [&](size_t bytes) -> char* {
        char* p = ws + off;
        off += (bytes + 255) & ~(size_t)255;
        return p;
    };
    int*   degcur = (int*)  alloc((size_t)2 * N_NODES * 4);  // deg | cursor, one memset
    int*   deg    = degcur;
    int*   cursor = degcur + N_NODES;
    int*   rowPtr = (int*)  alloc((size_t)(N_NODES + 1) * 4);
    int*   colIdx = (int*)  alloc((size_t)N_EDGES * 4);
    int*   blkTot = (int*)  alloc(256 * 4);
    float* dinv   = (float*)alloc((size_t)N_NODES * 4);
    unsigned short* W0t  = (unsigned short*)alloc((size_t)W0N * IN_F * 2);
    unsigned short* W1t  = (unsigned short*)alloc((size_t)W1N * HID_F * 2);
    unsigned short* xb   = (unsigned short*)alloc((size_t)N_NODES * IN_F * 2);
    unsigned short* Hg   = (unsigned short*)alloc((size_t)N_NODES * 256 * 2);
    unsigned short* Hm   = (unsigned short*)alloc((size_t)N_NODES * 128 * 2);
    unsigned short* H1g  = (unsigned short*)alloc((size_t)N_NODES * 80 * 2);
    unsigned short* H1m  = (unsigned short*)alloc((size_t)N_NODES * 40 * 2);
    unsigned short* hbuf = (unsigned short*)alloc((size_t)N_NODES * HID_F * 2);

    // 1. zero deg+cursor
    hipMemsetAsync(degcur, 0, (size_t)2 * N_NODES * 4, stream);
    // 2. fused prep: x->bf16, pack W0t, pack W1t, degree count
    k_prep<<<PREPB, 256, 0, stream>>>(x, xb, Wl0, Wh0, Wm0, W0t,
                                      Wl1, Wh1, Wm1, W1t, ei, deg);
    // 3-5. scan chain (dinv fused into scan1)
    k_scan1<<<NB, 256, 0, stream>>>(deg, rowPtr, blkTot, dinv);
    k_scan2<<<1, 256, 0, stream>>>(blkTot);
    k_scan3<<<NB, 256, 0, stream>>>(deg, blkTot, rowPtr);
    // 6. GEMM0 (bf16 A) with fused CSR fill
    {
        dim3 grid(3 + 8, (N_NODES + 127) / 128);   // 3 N-tiles + 8*391>=3125 fill blocks
        k_gemm_fill<<<grid, 256, 0, stream>>>(xb, W0t, Hg, 256, Hm, 128, 256,
                                              N_NODES, W0N, IN_F, 3,
                                              ei, rowPtr, cursor, colIdx);
    }
    // 7. layer-0 aggregate + epilogue
    k_layer0<<<N_NODES / 4, 256, 0, stream>>>(Hg, Hm, rowPtr, colIdx, dinv,
                                              al0, ah0, am0, att0, hbuf);
    // 8. GEMM1 (no fill blocks)
    {
        dim3 grid(1, (N_NODES + 127) / 128);
        k_gemm_fill<<<grid, 256, 0, stream>>>(hbuf, W1t, H1g, 80, H1m, 40, 80,
                                              N_NODES, W1N, HID_F, 1,
                                              nullptr, nullptr, nullptr, nullptr);
    }
    // 9. layer-1 aggregate + epilogue
    k_layer1<<<N_NODES / 4, 256, 0, stream>>>(H1g, H1m, rowPtr, colIdx, dinv,
                                              al1, ah1, am1, att1, out);
}

// Round 5
// 221.427 us; speedup vs baseline: 3.2347x; 1.0708x over previous
//
#include <hip/hip_runtime.h>
#include <math.h>

#define N_NODES 50000
#define N_EDGES 800000
#define IN_F    256
#define HID_F   128
#define OUT_F   40
#define W0N     (3*HID_F)   // 384
#define W1N     (3*OUT_F)   // 120
#define NB      ((N_NODES + 255) / 256)

// k_prep block ranges
#define XB   6250                        // x convert: 12.8M elems / (256*8)
#define P0B  ((IN_F * W0N) / 256)        // 384
#define P1B  ((HID_F * W1N) / 256)       // 60
#define CB0  (XB + P0B + P1B)            // 6694
#define CNTB ((N_EDGES + 255) / 256)     // 3125
#define PREPB (CB0 + CNTB)               // 9819

typedef __attribute__((ext_vector_type(8))) unsigned short ushort8;
typedef __attribute__((ext_vector_type(4))) unsigned short ushort4v;
typedef __attribute__((ext_vector_type(8))) __bf16 bf16x8;
typedef __attribute__((ext_vector_type(4))) float f32x4;
typedef __attribute__((ext_vector_type(2))) float f32x2;

static __device__ __forceinline__ float sigmoidf_(float x) {
    return 1.0f / (1.0f + expf(-x));
}

static __device__ __forceinline__ unsigned short f2bf(float f) {
    unsigned u = __float_as_uint(f);
    u += 0x7FFFu + ((u >> 16) & 1u);
    return (unsigned short)(u >> 16);
}

static __device__ __forceinline__ float bflo(unsigned u) { return __uint_as_float(u << 16); }
static __device__ __forceinline__ float bfhi(unsigned u) { return __uint_as_float(u & 0xffff0000u); }

// ---------------- fused prep: x->bf16 | pack W0^T | pack W1^T(k-perm) | count ----------------

__global__ __launch_bounds__(256) void k_prep(
        const float* __restrict__ x, unsigned short* __restrict__ xb,
        const float* __restrict__ Wl0, const float* __restrict__ Wh0,
        const float* __restrict__ Wm0, unsigned short* __restrict__ W0t,
        const float* __restrict__ Wl1, const float* __restrict__ Wh1,
        const float* __restrict__ Wm1, unsigned short* __restrict__ W1t,
        const int* __restrict__ ei, int* __restrict__ deg) {
    int b = blockIdx.x, t = threadIdx.x;
    if (b < XB) {
        size_t idx = (size_t)b * 2048 + t * 8;
        float4 f0 = *(const float4*)(x + idx);
        float4 f1 = *(const float4*)(x + idx + 4);
        ushort8 u;
        u[0]=f2bf(f0.x); u[1]=f2bf(f0.y); u[2]=f2bf(f0.z); u[3]=f2bf(f0.w);
        u[4]=f2bf(f1.x); u[5]=f2bf(f1.y); u[6]=f2bf(f1.z); u[7]=f2bf(f1.w);
        *(ushort8*)(xb + idx) = u;
    } else if (b < XB + P0B) {
        int i = (b - XB) * 256 + t;
        int n = i / IN_F, k = i % IN_F;
        float v;
        if (n < HID_F)            v = Wl0[k * HID_F + n];
        else if (n < 2 * HID_F)   v = Wh0[k * HID_F + (n - HID_F)];
        else                      v = Wm0[k * HID_F + (n - 2 * HID_F)];
        W0t[i] = f2bf(v);
    } else if (b < CB0) {
        int i = (b - XB - P0B) * 256 + t;
        int n = i / HID_F, kp = i % HID_F;
        // k-dim permuted to match hbuf's permuted layout: feat = g*64 + q*16 + c
        int k = ((kp >> 6) << 6) + ((kp & 3) << 4) + ((kp >> 2) & 15);
        float v;
        if (n < OUT_F)            v = Wl1[k * OUT_F + n];
        else if (n < 2 * OUT_F)   v = Wh1[k * OUT_F + (n - OUT_F)];
        else                      v = Wm1[k * OUT_F + (n - 2 * OUT_F)];
        W1t[i] = f2bf(v);
    } else {
        int e = (b - CB0) * 256 + t;
        if (e < N_EDGES) atomicAdd(&deg[ei[e]], 1);
    }
}

// ---------------- CSR scan ----------------

__global__ void k_scan1(const int* __restrict__ deg, int* __restrict__ rowPtr,
                        int* __restrict__ blkTot, float* __restrict__ dinv) {
    __shared__ int s[256];
    int t = threadIdx.x;
    int gid = blockIdx.x * 256 + t;
    int v = (gid < N_NODES) ? deg[gid] : 0;
    if (gid < N_NODES) dinv[gid] = 1.0f / (1.0f + (float)v);
    s[t] = v; __syncthreads();
    for (int d = 1; d < 256; d <<= 1) {
        int x = (t >= d) ? s[t - d] : 0;
        __syncthreads();
        s[t] += x;
        __syncthreads();
    }
    if (gid < N_NODES) rowPtr[gid] = s[t];
    if (t == 255) blkTot[blockIdx.x] = s[255];
}

__global__ void k_scan2(int* __restrict__ blk) {
    __shared__ int s[256];
    int t = threadIdx.x;
    int v = (t < NB) ? blk[t] : 0;
    s[t] = v; __syncthreads();
    for (int d = 1; d < 256; d <<= 1) {
        int x = (t >= d) ? s[t - d] : 0;
        __syncthreads();
        s[t] += x;
        __syncthreads();
    }
    if (t < NB) blk[t] = s[t] - v;
}

__global__ void k_scan3(const int* __restrict__ deg, const int* __restrict__ blkOff,
                        int* __restrict__ rowPtr) {
    int t = threadIdx.x;
    int gid = blockIdx.x * 256 + t;
    if (gid < N_NODES) rowPtr[gid] += blkOff[blockIdx.x] - deg[gid];
    if (gid == 0) rowPtr[N_NODES] = N_EDGES;
}

// ---------------- bf16 MFMA GEMM + optional fused CSR-fill ----------------
// tile 128x128, BK=32, 4 waves (2x2).
// EPI=0: plain bf16 split write: cols [0,nsplit)->C0(ld0), rest->C1(ld1).
// EPI=1: layer-0 write: Hs (bf16 perm), Hq (fp8 perm), HmP (bf16 perm).
//   permuted pos within 64-col group: pos = col*4 + n  <->  feat = n*16 + col

#define BKP 40   // 32 + 8 pad

template<int EPI>
__global__ __launch_bounds__(256) void k_gemm_fill(
        const unsigned short* __restrict__ A, const unsigned short* __restrict__ Bt,
        unsigned short* __restrict__ C0, int ld0,
        unsigned short* __restrict__ C1, int ld1, int nsplit,
        unsigned short* __restrict__ Hs, unsigned char* __restrict__ Hq,
        unsigned short* __restrict__ HmP,
        int M, int N, int K, int nxt,
        const int* __restrict__ ei, const int* __restrict__ rowPtr,
        int* __restrict__ cursor, int* __restrict__ colIdx) {
    __shared__ unsigned short As[128 * BKP];
    __shared__ unsigned short Bs[128 * BKP];
    int tid  = threadIdx.x;

    if ((int)blockIdx.x >= nxt) {
        int fid = (blockIdx.x - nxt) * gridDim.y + blockIdx.y;
        int e = fid * 256 + tid;
        if (e < N_EDGES) {
            int r = ei[e];
            int c = ei[N_EDGES + e];
            int pos = rowPtr[r] + atomicAdd(&cursor[r], 1);
            colIdx[pos] = c;
        }
        return;
    }

    int lane = tid & 63, wid = tid >> 6;
    int wr = wid >> 1, wc = wid & 1;
    int bm = blockIdx.y * 128, bn = blockIdx.x * 128;

    int srow = tid >> 1;
    int scol = (tid & 1) * 16;

    int garow = min(bm + srow, M - 1);
    int gbrow = min(bn + srow, N - 1);

    f32x4 acc[4][4];
#pragma unroll
    for (int m = 0; m < 4; ++m)
#pragma unroll
        for (int n = 0; n < 4; ++n)
            acc[m][n] = (f32x4)(0.0f);

    int kg = (lane >> 4) * 8;
    int rA = wr * 64 + (lane & 15);
    int rB = wc * 64 + (lane & 15);

    for (int k0 = 0; k0 < K; k0 += 32) {
        {
            const unsigned short* src = A + (size_t)garow * K + k0 + scol;
            *(ushort8*)&As[srow * BKP + scol]     = *(const ushort8*)(src);
            *(ushort8*)&As[srow * BKP + scol + 8] = *(const ushort8*)(src + 8);
        }
        {
            const unsigned short* src = Bt + (size_t)gbrow * K + k0 + scol;
            *(ushort8*)&Bs[srow * BKP + scol]     = *(const ushort8*)(src);
            *(ushort8*)&Bs[srow * BKP + scol + 8] = *(const ushort8*)(src + 8);
        }
        __syncthreads();

        bf16x8 a[4], b[4];
#pragma unroll
        for (int m = 0; m < 4; ++m)
            a[m] = __builtin_bit_cast(bf16x8, *(const ushort8*)&As[(rA + m * 16) * BKP + kg]);
#pragma unroll
        for (int n = 0; n < 4; ++n)
            b[n] = __builtin_bit_cast(bf16x8, *(const ushort8*)&Bs[(rB + n * 16) * BKP + kg]);
#pragma unroll
        for (int m = 0; m < 4; ++m)
#pragma unroll
            for (int n = 0; n < 4; ++n)
                acc[m][n] = __builtin_amdgcn_mfma_f32_16x16x32_bf16(a[m], b[n], acc[m][n], 0, 0, 0);
        __syncthreads();
    }

    int col  = lane & 15;
    int rsub = (lane >> 4) * 4;

    if (EPI == 0) {
#pragma unroll
        for (int m = 0; m < 4; ++m) {
            int gm0 = bm + wr * 64 + m * 16 + rsub;
#pragma unroll
            for (int n = 0; n < 4; ++n) {
                int gn = bn + wc * 64 + n * 16 + col;
                if (gn >= N) continue;
#pragma unroll
                for (int j = 0; j < 4; ++j) {
                    int gm = gm0 + j;
                    if (gm >= M) continue;
                    unsigned short b = f2bf(acc[m][n][j]);
                    if (gn < nsplit) C0[(size_t)gm * ld0 + gn] = b;
                    else             C1[(size_t)gm * ld1 + (gn - nsplit)] = b;
                }
            }
        }
    } else {
        // permuted writes; this thread covers pos base = bn + wc*64 + col*4
#pragma unroll
        for (int m = 0; m < 4; ++m) {
            int gm0 = bm + wr * 64 + m * 16 + rsub;
#pragma unroll
            for (int j = 0; j < 4; ++j) {
                int gm = gm0 + j;
                if (gm >= M) continue;
                float v0 = acc[m][0][j], v1 = acc[m][1][j];
                float v2 = acc[m][2][j], v3 = acc[m][3][j];
                ushort4v o;
                o[0] = f2bf(v0); o[1] = f2bf(v1); o[2] = f2bf(v2); o[3] = f2bf(v3);
                if (bn < 256) {
                    int pos = bn + wc * 64 + col * 4;
                    *(ushort4v*)&Hs[(size_t)gm * 256 + pos] = o;
                    int pk = 0;
                    pk = __builtin_amdgcn_cvt_pk_fp8_f32(v0, v1, pk, false);
                    pk = __builtin_amdgcn_cvt_pk_fp8_f32(v2, v3, pk, true);
                    *(unsigned*)&Hq[(size_t)gm * 256 + pos] = (unsigned)pk;
                } else {
                    int pos = wc * 64 + col * 4;
                    *(ushort4v*)&HmP[(size_t)gm * 128 + pos] = o;
                }
            }
        }
    }
}

// ---------------- layer 0: wave-per-node, fp8 neighbor gather + ACM epilogue ----------------
// Hq fp8 perm [256 B/row]; Hs bf16 perm [256]; HmP bf16 perm [128].
// lane's 4 true feats: c_q = (lane>>4)*64 + q*16 + (lane&15); lanes<32 = hl, >=32 = hh.

__global__ __launch_bounds__(256) void k_layer0(
        const unsigned short* __restrict__ Hs, const unsigned char* __restrict__ Hq,
        const unsigned short* __restrict__ HmP,
        const int* __restrict__ rowPtr, const int* __restrict__ colIdx,
        const float* __restrict__ dinv,
        const float* __restrict__ al, const float* __restrict__ ah,
        const float* __restrict__ am, const float* __restrict__ att,
        unsigned short* __restrict__ hout) {
    int lane = threadIdx.x & 63;
    int i = blockIdx.x * 4 + (threadIdx.x >> 6);

    int p0 = rowPtr[i], p1 = rowPtr[i + 1];
    float a0 = 0.f, a1 = 0.f, a2 = 0.f, a3 = 0.f;
    int off4 = lane * 4;
    int p = p0;
    for (; p + 7 < p1; p += 8) {
        int j[8];
#pragma unroll
        for (int q = 0; q < 8; ++q) j[q] = colIdx[p + q];
        unsigned w[8];
#pragma unroll
        for (int q = 0; q < 8; ++q) w[q] = *(const unsigned*)(Hq + (size_t)j[q] * 256 + off4);
#pragma unroll
        for (int q = 0; q < 8; ++q) {
            f32x2 d0 = __builtin_amdgcn_cvt_pk_f32_fp8((int)w[q], false);
            f32x2 d1 = __builtin_amdgcn_cvt_pk_f32_fp8((int)w[q], true);
            a0 += d0.x; a1 += d0.y; a2 += d1.x; a3 += d1.y;
        }
    }
    for (; p < p1; ++p) {
        int j = colIdx[p];
        unsigned w = *(const unsigned*)(Hq + (size_t)j * 256 + off4);
        f32x2 d0 = __builtin_amdgcn_cvt_pk_f32_fp8((int)w, false);
        f32x2 d1 = __builtin_amdgcn_cvt_pk_f32_fp8((int)w, true);
        a0 += d0.x; a1 += d0.y; a2 += d1.x; a3 += d1.y;
    }

    uint2 sv = *(const uint2*)(Hs + (size_t)i * 256 + off4);   // 4 bf16 self vals
    float s0 = bflo(sv.x), s1 = bfhi(sv.x), s2 = bflo(sv.y), s3 = bfhi(sv.y);
    float di = dinv[i];
    float l0 = di * (s0 + a0), l1 = di * (s1 + a1);
    float l2 = di * (s2 + a2), l3 = di * (s3 + a3);

    float ol0 = fmaxf(l0, 0.f), ol1 = fmaxf(l1, 0.f);
    float ol2 = fmaxf(l2, 0.f), ol3 = fmaxf(l3, 0.f);
    float oh0 = fmaxf(s0 - l0, 0.f), oh1 = fmaxf(s1 - l1, 0.f);
    float oh2 = fmaxf(s2 - l2, 0.f), oh3 = fmaxf(s3 - l3, 0.f);

    int c0 = ((lane >> 4) << 6) + (lane & 15);   // true feat of q=0

    float om0 = 0.f, om1 = 0.f, om2 = 0.f, om3 = 0.f;
    float prA, prM = 0.f;
    if (lane < 32) {
        uint2 hv = *(const uint2*)(HmP + (size_t)i * 128 + off4);
        om0 = fmaxf(bflo(hv.x), 0.f); om1 = fmaxf(bfhi(hv.x), 0.f);
        om2 = fmaxf(bflo(hv.y), 0.f); om3 = fmaxf(bfhi(hv.y), 0.f);
        prA = ol0 * al[c0] + ol1 * al[c0 + 16] + ol2 * al[c0 + 32] + ol3 * al[c0 + 48];
        prM = om0 * am[c0] + om1 * am[c0 + 16] + om2 * am[c0 + 32] + om3 * am[c0 + 48];
    } else {
        int ch = c0 - 128;
        prA = oh0 * ah[ch] + oh1 * ah[ch + 16] + oh2 * ah[ch + 32] + oh3 * ah[ch + 48];
    }

#pragma unroll
    for (int d = 1; d < 32; d <<= 1) prA += __shfl_xor(prA, d);
#pragma unroll
    for (int d = 1; d < 32; d <<= 1) prM += __shfl_xor(prM, d);
    float g0 = __shfl(prA, 0);
    float g1 = __shfl(prA, 32);
    float g2 = __shfl(prM, 0);

    float sg0 = sigmoidf_(g0), sg1 = sigmoidf_(g1), sg2 = sigmoidf_(g2);
    const float inv3 = (1.0f / 3.0f);
    float e0 = (sg0 * att[0] + sg1 * att[3] + sg2 * att[6]) * inv3;
    float e1 = (sg0 * att[1] + sg1 * att[4] + sg2 * att[7]) * inv3;
    float e2 = (sg0 * att[2] + sg1 * att[5] + sg2 * att[8]) * inv3;
    float mx = fmaxf(e0, fmaxf(e1, e2));
    float x0 = expf(e0 - mx), x1 = expf(e1 - mx), x2 = expf(e2 - mx);
    float inv = 1.0f / (x0 + x1 + x2);
    float c0f = 3.0f * inv * x0, c1f = 3.0f * inv * x1, c2f = 3.0f * inv * x2;

    int src = lane | 32;
    float th0 = __shfl(oh0, src), th1 = __shfl(oh1, src);
    float th2 = __shfl(oh2, src), th3 = __shfl(oh3, src);

    if (lane < 32) {
        // hbuf permuted: pos p = lane*4+q -> true feat c_q (matches W1t k-perm)
        ushort4v o;
        o[0] = f2bf(c0f * ol0 + c1f * th0 + c2f * om0);
        o[1] = f2bf(c0f * ol1 + c1f * th1 + c2f * om1);
        o[2] = f2bf(c0f * ol2 + c1f * th2 + c2f * om2);
        o[3] = f2bf(c0f * ol3 + c1f * th3 + c2f * om3);
        *(ushort4v*)&hout[(size_t)i * 128 + off4] = o;
    }
}

// ---------------- layer 1: wave-per-node aggregate + ACM epilogue ----------------
// H1g[i][c] bf16: c<40 hl, c>=40 hh (80 cols). H1m: hm (40). lanes 0..39 active.

__global__ __launch_bounds__(256) void k_layer1(
        const unsigned short* __restrict__ H1g, const unsigned short* __restrict__ H1m,
        const int* __restrict__ rowPtr, const int* __restrict__ colIdx,
        const float* __restrict__ dinv,
        const float* __restrict__ al, const float* __restrict__ ah,
        const float* __restrict__ am, const float* __restrict__ att,
        float* __restrict__ out) {
    int lane = threadIdx.x & 63;
    int i = blockIdx.x * 4 + (threadIdx.x >> 6);

    int p0 = rowPtr[i], p1 = rowPtr[i + 1];
    float a0 = 0.f, a1 = 0.f;
    int off = lane * 2;
    bool active = lane < 40;
    int p = p0;
    if (active) {
        for (; p + 7 < p1; p += 8) {
            int j[8];
#pragma unroll
            for (int q = 0; q < 8; ++q) j[q] = colIdx[p + q];
            unsigned v[8];
#pragma unroll
            for (int q = 0; q < 8; ++q) v[q] = *(const unsigned*)(H1g + (size_t)j[q] * 80 + off);
#pragma unroll
            for (int q = 0; q < 8; ++q) { a0 += bflo(v[q]); a1 += bfhi(v[q]); }
        }
        for (; p < p1; ++p) {
            int j = colIdx[p];
            unsigned v = *(const unsigned*)(H1g + (size_t)j * 80 + off);
            a0 += bflo(v); a1 += bfhi(v);
        }
    }

    float s0 = 0.f, s1 = 0.f;
    if (active) {
        unsigned sv = *(const unsigned*)(H1g + (size_t)i * 80 + off);
        s0 = bflo(sv); s1 = bfhi(sv);
    }
    float di = dinv[i];
    float l0 = di * (s0 + a0), l1 = di * (s1 + a1);

    float ol0 = fmaxf(l0, 0.f), ol1 = fmaxf(l1, 0.f);
    float oh0 = fmaxf(s0 - l0, 0.f), oh1 = fmaxf(s1 - l1, 0.f);

    float om0 = 0.f, om1 = 0.f;
    float r0 = 0.f, r1 = 0.f, r2 = 0.f;
    if (lane < 20) {
        unsigned hv = *(const unsigned*)(H1m + (size_t)i * 40 + off);
        om0 = fmaxf(bflo(hv), 0.f); om1 = fmaxf(bfhi(hv), 0.f);
        float2 alv = *(const float2*)(al + off);
        float2 amv = *(const float2*)(am + off);
        r0 = ol0 * alv.x + ol1 * alv.y;
        r2 = om0 * amv.x + om1 * amv.y;
    } else if (lane < 40) {
        float2 ahv = *(const float2*)(ah + (off - 40));
        r1 = oh0 * ahv.x + oh1 * ahv.y;
    }

#pragma unroll
    for (int d = 1; d < 64; d <<= 1) r0 += __shfl_xor(r0, d);
#pragma unroll
    for (int d = 1; d < 64; d <<= 1) r1 += __shfl_xor(r1, d);
#pragma unroll
    for (int d = 1; d < 64; d <<= 1) r2 += __shfl_xor(r2, d);

    float sg0 = sigmoidf_(r0), sg1 = sigmoidf_(r1), sg2 = sigmoidf_(r2);
    const float inv3 = (1.0f / 3.0f);
    float e0 = (sg0 * att[0] + sg1 * att[3] + sg2 * att[6]) * inv3;
    float e1 = (sg0 * att[1] + sg1 * att[4] + sg2 * att[7]) * inv3;
    float e2 = (sg0 * att[2] + sg1 * att[5] + sg2 * att[8]) * inv3;
    float mx = fmaxf(e0, fmaxf(e1, e2));
    float x0 = expf(e0 - mx), x1 = expf(e1 - mx), x2 = expf(e2 - mx);
    float inv = 1.0f / (x0 + x1 + x2);
    float c0 = 3.0f * inv * x0, c1 = 3.0f * inv * x1, c2 = 3.0f * inv * x2;

    int src = (lane + 20) & 63;
    float th0 = __shfl(oh0, src), th1 = __shfl(oh1, src);

    if (lane < 20) {
        float2 o;
        o.x = c0 * ol0 + c1 * th0 + c2 * om0;
        o.y = c0 * ol1 + c1 * th1 + c2 * om1;
        *(float2*)&out[(size_t)i * 40 + off] = o;
    }
}

// ---------------- launch ----------------

extern "C" void kernel_launch(void* const* d_in, const int* in_sizes, int n_in,
                              void* d_out, int out_size, void* d_ws, size_t ws_size,
                              hipStream_t stream) {
    const float* x    = (const float*)d_in[0];
    const int*   ei   = (const int*)d_in[1];
    const float* Wl0  = (const float*)d_in[2];
    const float* Wh0  = (const float*)d_in[3];
    const float* Wm0  = (const float*)d_in[4];
    const float* al0  = (const float*)d_in[5];
    const float* ah0  = (const float*)d_in[6];
    const float* am0  = (const float*)d_in[7];
    const float* att0 = (const float*)d_in[8];
    const float* Wl1  = (const float*)d_in[9];
    const float* Wh1  = (const float*)d_in[10];
    const float* Wm1  = (const float*)d_in[11];
    const float* al1  = (const float*)d_in[12];
    const float* ah1  = (const float*)d_in[13];
    const float* am1  = (const float*)d_in[14];
    const float* att1 = (const float*)d_in[15];
    float* out = (float*)d_out;

    char* ws = (char*)d_ws;
    size_t off = 0;
    auto alloc = [&](size_t bytes) -> char* {
        char* p = ws + off;
        off += (bytes + 255) & ~(size_t)255;
        return p;
    };
    int*   degcur = (int*)  alloc((size_t)2 * N_NODES * 4);  // deg | cursor
    int*   deg    = degcur;
    int*   cursor = degcur + N_NODES;
    int*   rowPtr = (int*)  alloc((size_t)(N_NODES + 1) * 4);
    int*   colIdx = (int*)  alloc((size_t)N_EDGES * 4);
    int*   blkTot = (int*)  alloc(256 * 4);
    float* dinv   = (float*)alloc((size_t)N_NODES * 4);
    unsigned short* W0t  = (unsigned short*)alloc((size_t)W0N * IN_F * 2);
    unsigned short* W1t  = (unsigned short*)alloc((size_t)W1N * HID_F * 2);
    unsigned short* xb   = (unsigned short*)alloc((size_t)N_NODES * IN_F * 2);
    unsigned short* Hs   = (unsigned short*)alloc((size_t)N_NODES * 256 * 2);
    unsigned char*  Hq   = (unsigned char*) alloc((size_t)N_NODES * 256);
    unsigned short* HmP  = (unsigned short*)alloc((size_t)N_NODES * 128 * 2);
    unsigned short* H1g  = (unsigned short*)alloc((size_t)N_NODES * 80 * 2);
    unsigned short* H1m  = (unsigned short*)alloc((size_t)N_NODES * 40 * 2);
    unsigned short* hbuf = (unsigned short*)alloc((size_t)N_NODES * HID_F * 2);

    // 1. zero deg+cursor
    hipMemsetAsync(degcur, 0, (size_t)2 * N_NODES * 4, stream);
    // 2. fused prep
    k_prep<<<PREPB, 256, 0, stream>>>(x, xb, Wl0, Wh0, Wm0, W0t,
                                      Wl1, Wh1, Wm1, W1t, ei, deg);
    // 3-5. scan chain
    k_scan1<<<NB, 256, 0, stream>>>(deg, rowPtr, blkTot, dinv);
    k_scan2<<<1, 256, 0, stream>>>(blkTot);
    k_scan3<<<NB, 256, 0, stream>>>(deg, blkTot, rowPtr);
    // 6. GEMM0 (layer-0 epilogue: Hs/Hq/HmP) with fused CSR fill
    {
        dim3 grid(3 + 8, (N_NODES + 127) / 128);
        k_gemm_fill<1><<<grid, 256, 0, stream>>>(xb, W0t,
                                                 nullptr, 0, nullptr, 0, 0,
                                                 Hs, Hq, HmP,
                                                 N_NODES, W0N, IN_F, 3,
                                                 ei, rowPtr, cursor, colIdx);
    }
    // 7. layer-0 aggregate + epilogue
    k_layer0<<<N_NODES / 4, 256, 0, stream>>>(Hs, Hq, HmP, rowPtr, colIdx, dinv,
                                              al0, ah0, am0, att0, hbuf);
    // 8. GEMM1 (plain epilogue -> H1g/H1m)
    {
        dim3 grid(1, (N_NODES + 127) / 128);
        k_gemm_fill<0><<<grid, 256, 0, stream>>>(hbuf, W1t,
                                                 H1g, 80, H1m, 40, 80,
                                                 nullptr, nullptr, nullptr,
                                                 N_NODES, W1N, HID_F, 1,
                                                 nullptr, nullptr, nullptr, nullptr);
    }
    // 9. layer-1 aggregate + epilogue
    k_layer1<<<N_NODES / 4, 256, 0, stream>>>(H1g, H1m, rowPtr, colIdx, dinv,
                                              al1, ah1, am1, att1, out);
}